// Round 1
// baseline (1636.556 us; speedup 1.0000x reference)
//
#include <hip/hip_runtime.h>
#include <hip/hip_bf16.h>
#include <math.h>

#define D 128

// ---------- helpers ----------
__device__ __forceinline__ unsigned ord_enc(float f) {
  unsigned u = __float_as_uint(f);
  return (u & 0x80000000u) ? ~u : (u | 0x80000000u);
}
__device__ __forceinline__ float ord_dec(unsigned u) {
  u = (u & 0x80000000u) ? (u ^ 0x80000000u) : ~u;
  return __uint_as_float(u);
}
__device__ __forceinline__ float sigmoidf_(float x) { return 1.f / (1.f + __expf(-x)); }

// ---------- Wh[n,h,d] = sum_k h[n,k] * W[h,k,d] ----------
template <int H>
__global__ void __launch_bounds__(256) k_gemm_wh(const float* __restrict__ hin,
                                                 const float* __restrict__ W,
                                                 float* __restrict__ Wh) {
  __shared__ float hs[16][D];
  const int head = blockIdx.y;
  const int n0 = blockIdx.x * 16;
  const int tid = threadIdx.x;
  for (int i = tid; i < 16 * D; i += 256) {
    hs[i >> 7][i & 127] = hin[(size_t)(n0 + (i >> 7)) * D + (i & 127)];
  }
  __syncthreads();
  const int d = tid & 127;
  const int half = tid >> 7;
  const float* Wp = W + (size_t)head * D * D + d;
  float acc[8] = {};
  for (int k0 = 0; k0 < D; k0 += 4) {
    float w0 = Wp[(k0 + 0) * D], w1 = Wp[(k0 + 1) * D];
    float w2 = Wp[(k0 + 2) * D], w3 = Wp[(k0 + 3) * D];
#pragma unroll
    for (int i = 0; i < 8; ++i) {
      float4 hv = *(const float4*)&hs[half * 8 + i][k0];
      acc[i] += hv.x * w0 + hv.y * w1 + hv.z * w2 + hv.w * w3;
    }
  }
#pragma unroll
  for (int i = 0; i < 8; ++i) {
    Wh[((size_t)(n0 + half * 8 + i) * H + head) * D + d] = acc[i];
  }
}

// ---------- es[n,h] = dot(Wh[n,h,:], a_src[h,:]), ed likewise ----------
template <int H>
__global__ void __launch_bounds__(256) k_es_ed(const float* __restrict__ Wh,
                                               const float* __restrict__ a_src,
                                               const float* __restrict__ a_dst,
                                               float* __restrict__ es,
                                               float* __restrict__ ed, int NH) {
  int w = blockIdx.x * 4 + (threadIdx.x >> 6);
  int lane = threadIdx.x & 63;
  if (w >= NH) return;
  int hh = w % H;
  const float* row = Wh + (size_t)w * D;
  float x0 = row[lane], x1 = row[lane + 64];
  float s = x0 * a_src[hh * D + lane] + x1 * a_src[hh * D + lane + 64];
  float t = x0 * a_dst[hh * D + lane] + x1 * a_dst[hh * D + lane + 64];
#pragma unroll
  for (int off = 32; off; off >>= 1) {
    s += __shfl_down(s, off);
    t += __shfl_down(t, off);
  }
  if (lane == 0) {
    es[w] = s;
    ed[w] = t;
  }
}

// ---------- edge pass 1: segment max ----------
template <int H>
__global__ void __launch_bounds__(256) k_edge1(const int* __restrict__ src, const int* __restrict__ dst,
                                               const float* __restrict__ es, const float* __restrict__ ed,
                                               unsigned* __restrict__ mbits, int E) {
  int e = blockIdx.x * 256 + threadIdx.x;
  if (e >= E) return;
  int s = src[e], t = dst[e];
#pragma unroll
  for (int h = 0; h < H; ++h) {
    float v = es[s * H + h] + ed[t * H + h];
    v = v > 0.f ? v : 0.2f * v;
    atomicMax(&mbits[t * H + h], ord_enc(v));
  }
}

__global__ void __launch_bounds__(256) k_decode(unsigned* __restrict__ m, int n) {
  int i = blockIdx.x * 256 + threadIdx.x;
  if (i < n) ((float*)m)[i] = ord_dec(m[i]);
}

// ---------- edge pass 2: segment sum of exp(e - m[dst]) ----------
template <int H>
__global__ void __launch_bounds__(256) k_edge2(const int* __restrict__ src, const int* __restrict__ dst,
                                               const float* __restrict__ es, const float* __restrict__ ed,
                                               const float* __restrict__ m, float* __restrict__ den, int E) {
  int e = blockIdx.x * 256 + threadIdx.x;
  if (e >= E) return;
  int s = src[e], t = dst[e];
#pragma unroll
  for (int h = 0; h < H; ++h) {
    float v = es[s * H + h] + ed[t * H + h];
    v = v > 0.f ? v : 0.2f * v;
    float w = __expf(v - m[t * H + h]);
    atomicAdd(&den[t * H + h], w);
  }
}

// ---------- edge pass 3: agg[dst,d] += sum_h (alpha/H) * Wh[src,h,d] ----------
template <int H>
__global__ void __launch_bounds__(256) k_edge3(const int* __restrict__ src, const int* __restrict__ dst,
                                               const float* __restrict__ es, const float* __restrict__ ed,
                                               const float* __restrict__ m, const float* __restrict__ den,
                                               const float* __restrict__ Wh, float* __restrict__ agg, int E) {
  int idx = blockIdx.x * 256 + threadIdx.x;  // = e*128 + d
  int e = idx >> 7;
  int d = idx & 127;
  if (e >= E) return;
  int s = src[e], t = dst[e];
  float sum = 0.f;
#pragma unroll
  for (int h = 0; h < H; ++h) {
    float v = es[s * H + h] + ed[t * H + h];
    v = v > 0.f ? v : 0.2f * v;
    float w = __expf(v - m[t * H + h]);
    float alpha = w / den[t * H + h];
    sum += alpha * Wh[((size_t)s * H + h) * D + d];
  }
  atomicAdd(&agg[(size_t)t * D + d], sum * (1.0f / H));
}

// ---------- layer-1 epilogue: h_out = elu(agg) ----------
__global__ void __launch_bounds__(256) k_elu(const float* __restrict__ agg, float* __restrict__ out, int n) {
  int i = blockIdx.x * 256 + threadIdx.x;
  if (i >= n) return;
  float x = agg[i];
  out[i] = x > 0.f ? x : expm1f(x);
}

// ---------- GRU epilogue: out = elu(agg); h_out = GRUCell(out, hin) ----------
__global__ void __launch_bounds__(128) k_gru(const float* __restrict__ agg, const float* __restrict__ hin,
                                             const float* __restrict__ WihT, const float* __restrict__ WhhT,
                                             const float* __restrict__ bih, const float* __restrict__ bhh,
                                             float* __restrict__ hout) {
  __shared__ float xs[8][D];
  __shared__ float hsm[8][D];
  const int n0 = blockIdx.x * 8;
  const int tid = threadIdx.x;  // 128
  for (int i = tid; i < 8 * D; i += 128) {
    int r = i >> 7, c = i & 127;
    float x = agg[(size_t)(n0 + r) * D + c];
    xs[r][c] = x > 0.f ? x : expm1f(x);
    hsm[r][c] = hin[(size_t)(n0 + r) * D + c];
  }
  __syncthreads();
  const int d = tid;
  float air[8] = {}, aiz[8] = {}, ain[8] = {}, ahr[8] = {}, ahz[8] = {}, ahn[8] = {};
  for (int k0 = 0; k0 < D; k0 += 4) {
    float wi0[4], wi1[4], wi2[4], wh0[4], wh1[4], wh2[4];
#pragma unroll
    for (int q = 0; q < 4; ++q) {
      wi0[q] = WihT[(k0 + q) * 384 + d];
      wi1[q] = WihT[(k0 + q) * 384 + 128 + d];
      wi2[q] = WihT[(k0 + q) * 384 + 256 + d];
      wh0[q] = WhhT[(k0 + q) * 384 + d];
      wh1[q] = WhhT[(k0 + q) * 384 + 128 + d];
      wh2[q] = WhhT[(k0 + q) * 384 + 256 + d];
    }
#pragma unroll
    for (int i = 0; i < 8; ++i) {
      float4 xv = *(const float4*)&xs[i][k0];
      float4 hv = *(const float4*)&hsm[i][k0];
      air[i] += xv.x * wi0[0] + xv.y * wi0[1] + xv.z * wi0[2] + xv.w * wi0[3];
      aiz[i] += xv.x * wi1[0] + xv.y * wi1[1] + xv.z * wi1[2] + xv.w * wi1[3];
      ain[i] += xv.x * wi2[0] + xv.y * wi2[1] + xv.z * wi2[2] + xv.w * wi2[3];
      ahr[i] += hv.x * wh0[0] + hv.y * wh0[1] + hv.z * wh0[2] + hv.w * wh0[3];
      ahz[i] += hv.x * wh1[0] + hv.y * wh1[1] + hv.z * wh1[2] + hv.w * wh1[3];
      ahn[i] += hv.x * wh2[0] + hv.y * wh2[1] + hv.z * wh2[2] + hv.w * wh2[3];
    }
  }
  const float bi0 = bih[d], bi1 = bih[128 + d], bi2 = bih[256 + d];
  const float bh0 = bhh[d], bh1 = bhh[128 + d], bh2 = bhh[256 + d];
#pragma unroll
  for (int i = 0; i < 8; ++i) {
    float r = sigmoidf_(air[i] + bi0 + ahr[i] + bh0);
    float z = sigmoidf_(aiz[i] + bi1 + ahz[i] + bh1);
    float nn = tanhf(ain[i] + bi2 + r * (ahn[i] + bh2));
    float hprev = hsm[i][d];
    hout[(size_t)(n0 + i) * D + d] = (1.f - z) * nn + z * hprev;
  }
}

// ---------- transpose [rows,cols] -> [cols,rows] ----------
__global__ void __launch_bounds__(256) k_transpose(const float* __restrict__ W, float* __restrict__ WT,
                                                   int rows, int cols) {
  int i = blockIdx.x * 256 + threadIdx.x;
  if (i >= rows * cols) return;
  int r = i / cols, c = i % cols;
  WT[c * rows + r] = W[i];
}

// ---------- final: out[n] = sigmoid(dot(h[n,:], W5) + b5) ----------
__global__ void __launch_bounds__(256) k_final(const float* __restrict__ h, const float* __restrict__ W5,
                                               const float* __restrict__ b5, float* __restrict__ out, int N) {
  int w = blockIdx.x * 4 + (threadIdx.x >> 6);
  int lane = threadIdx.x & 63;
  if (w >= N) return;
  float x = h[(size_t)w * D + lane] * W5[lane] + h[(size_t)w * D + lane + 64] * W5[lane + 64];
#pragma unroll
  for (int off = 32; off; off >>= 1) x += __shfl_down(x, off);
  if (lane == 0) out[w] = sigmoidf_(x + b5[0]);
}

// ---------- host-side one layer ----------
template <int H>
static void run_layer(const float* hin, const float* W, const float* a_s, const float* a_d,
                      const float* WihT, const float* WhhT, const float* bih, const float* bhh,
                      float* Wh, float* es, float* ed, unsigned* mbits, float* den, float* agg,
                      float* hout, const int* src, const int* dst, int N, int E, hipStream_t stream) {
  dim3 g1(N / 16, H);
  k_gemm_wh<H><<<g1, 256, 0, stream>>>(hin, W, Wh);
  const int NH = N * H;
  k_es_ed<H><<<(NH + 3) / 4, 256, 0, stream>>>(Wh, a_s, a_d, es, ed, NH);
  hipMemsetAsync(mbits, 0, (size_t)NH * 4, stream);
  hipMemsetAsync(den, 0, (size_t)NH * 4, stream);
  hipMemsetAsync(agg, 0, (size_t)N * D * 4, stream);
  k_edge1<H><<<(E + 255) / 256, 256, 0, stream>>>(src, dst, es, ed, mbits, E);
  k_decode<<<(NH + 255) / 256, 256, 0, stream>>>(mbits, NH);
  k_edge2<H><<<(E + 255) / 256, 256, 0, stream>>>(src, dst, es, ed, (const float*)mbits, den, E);
  {
    int total = E * D;  // 40.96M, fits int
    k_edge3<H><<<(total + 255) / 256, 256, 0, stream>>>(src, dst, es, ed, (const float*)mbits, den, Wh, agg, E);
  }
  if (WihT) {
    k_gru<<<N / 8, 128, 0, stream>>>(agg, hin, WihT, WhhT, bih, bhh, hout);
  } else {
    k_elu<<<(N * D + 255) / 256, 256, 0, stream>>>(agg, hout, N * D);
  }
}

extern "C" void kernel_launch(void* const* d_in, const int* in_sizes, int n_in,
                              void* d_out, int out_size, void* d_ws, size_t ws_size,
                              hipStream_t stream) {
  const float* h0 = (const float*)d_in[0];
  const int* ei = (const int*)d_in[1];
  const float* W1 = (const float*)d_in[2];
  const float* as1 = (const float*)d_in[3];
  const float* ad1 = (const float*)d_in[4];
  const float* W2 = (const float*)d_in[5];
  const float* as2 = (const float*)d_in[6];
  const float* ad2 = (const float*)d_in[7];
  const float* W3 = (const float*)d_in[8];
  const float* as3 = (const float*)d_in[9];
  const float* ad3 = (const float*)d_in[10];
  const float* W4 = (const float*)d_in[11];
  const float* as4 = (const float*)d_in[12];
  const float* ad4 = (const float*)d_in[13];
  const float* Wih = (const float*)d_in[14];
  const float* Whh = (const float*)d_in[15];
  const float* bih = (const float*)d_in[16];
  const float* bhh = (const float*)d_in[17];
  const float* W5 = (const float*)d_in[18];
  const float* b5 = (const float*)d_in[19];

  const int N = in_sizes[0] / D;  // 20000
  const int E = in_sizes[1] / 2;  // 320000
  const int* src = ei;
  const int* dst = ei + E;

  // workspace layout (floats)
  float* ws = (float*)d_ws;
  float* Wh = ws;                         // N*4*D      = 10,240,000
  float* agg = Wh + (size_t)N * 4 * D;    // N*D        =  2,560,000
  float* hA = agg + (size_t)N * D;        // N*D
  float* hB = hA + (size_t)N * D;         // N*D
  float* es = hB + (size_t)N * D;         // N*4
  float* ed = es + (size_t)N * 4;         // N*4
  unsigned* mbits = (unsigned*)(ed + (size_t)N * 4);  // N*4
  float* den = (float*)mbits + (size_t)N * 4;         // N*4
  float* WihT = den + (size_t)N * 4;      // 128*384
  float* WhhT = WihT + 384 * 128;         // 128*384

  // transpose GRU weights once
  k_transpose<<<(384 * 128 + 255) / 256, 256, 0, stream>>>(Wih, WihT, 384, 128);
  k_transpose<<<(384 * 128 + 255) / 256, 256, 0, stream>>>(Whh, WhhT, 384, 128);

  // layer 1: H=4, no GRU
  run_layer<4>(h0, W1, as1, ad1, nullptr, nullptr, nullptr, nullptr,
               Wh, es, ed, mbits, den, agg, hA, src, dst, N, E, stream);
  // layer 2: H=4, GRU
  run_layer<4>(hA, W2, as2, ad2, WihT, WhhT, bih, bhh,
               Wh, es, ed, mbits, den, agg, hB, src, dst, N, E, stream);
  // layer 3: H=4, GRU
  run_layer<4>(hB, W3, as3, ad3, WihT, WhhT, bih, bhh,
               Wh, es, ed, mbits, den, agg, hA, src, dst, N, E, stream);
  // layer 4: H=1, GRU
  run_layer<1>(hA, W4, as4, ad4, WihT, WhhT, bih, bhh,
               Wh, es, ed, mbits, den, agg, hB, src, dst, N, E, stream);

  // output head
  k_final<<<(N + 3) / 4, 256, 0, stream>>>(hB, W5, b5, (float*)d_out, N);
}

// Round 2
// 929.911 us; speedup vs baseline: 1.7599x; 1.7599x over previous
//
#include <hip/hip_runtime.h>
#include <hip/hip_bf16.h>
#include <math.h>

#define D 128

__device__ __forceinline__ float sigmoidf_(float x) { return 1.f / (1.f + __expf(-x)); }

// ---------- Wh[n,h,d] = sum_k h[n,k] * W[h,k,d] ----------
template <int H>
__global__ void __launch_bounds__(256) k_gemm_wh(const float* __restrict__ hin,
                                                 const float* __restrict__ W,
                                                 float* __restrict__ Wh) {
  __shared__ float hs[16][D];
  const int head = blockIdx.y;
  const int n0 = blockIdx.x * 16;
  const int tid = threadIdx.x;
  for (int i = tid; i < 16 * D; i += 256) {
    hs[i >> 7][i & 127] = hin[(size_t)(n0 + (i >> 7)) * D + (i & 127)];
  }
  __syncthreads();
  const int d = tid & 127;
  const int half = tid >> 7;
  const float* Wp = W + (size_t)head * D * D + d;
  float acc[8] = {};
  for (int k0 = 0; k0 < D; k0 += 4) {
    float w0 = Wp[(k0 + 0) * D], w1 = Wp[(k0 + 1) * D];
    float w2 = Wp[(k0 + 2) * D], w3 = Wp[(k0 + 3) * D];
#pragma unroll
    for (int i = 0; i < 8; ++i) {
      float4 hv = *(const float4*)&hs[half * 8 + i][k0];
      acc[i] += hv.x * w0 + hv.y * w1 + hv.z * w2 + hv.w * w3;
    }
  }
#pragma unroll
  for (int i = 0; i < 8; ++i) {
    Wh[((size_t)(n0 + half * 8 + i) * H + head) * D + d] = acc[i];
  }
}

// ---------- es[n,h] = dot(Wh[n,h,:], a_src[h,:]), ed likewise ----------
template <int H>
__global__ void __launch_bounds__(256) k_es_ed(const float* __restrict__ Wh,
                                               const float* __restrict__ a_src,
                                               const float* __restrict__ a_dst,
                                               float* __restrict__ es,
                                               float* __restrict__ ed, int NH) {
  int w = blockIdx.x * 4 + (threadIdx.x >> 6);
  int lane = threadIdx.x & 63;
  if (w >= NH) return;
  int hh = w % H;
  const float* row = Wh + (size_t)w * D;
  float x0 = row[lane], x1 = row[lane + 64];
  float s = x0 * a_src[hh * D + lane] + x1 * a_src[hh * D + lane + 64];
  float t = x0 * a_dst[hh * D + lane] + x1 * a_dst[hh * D + lane + 64];
#pragma unroll
  for (int off = 32; off; off >>= 1) {
    s += __shfl_down(s, off);
    t += __shfl_down(t, off);
  }
  if (lane == 0) {
    es[w] = s;
    ed[w] = t;
  }
}

// ---------- CSR build ----------
__global__ void __launch_bounds__(256) k_hist(const int* __restrict__ dst, int* __restrict__ deg, int E) {
  int e = blockIdx.x * 256 + threadIdx.x;
  if (e < E) atomicAdd(&deg[dst[e]], 1);
}

__global__ void __launch_bounds__(1024) k_scan(const int* __restrict__ deg, int* __restrict__ rowptr,
                                               int* __restrict__ fill, int N) {
  __shared__ int part[1024];
  const int tid = threadIdx.x;
  const int chunk = (N + 1023) / 1024;
  const int b = tid * chunk;
  const int e = min(N, b + chunk);
  int s = 0;
  for (int i = b; i < e; ++i) s += deg[i];
  part[tid] = s;
  __syncthreads();
  for (int off = 1; off < 1024; off <<= 1) {
    int v = (tid >= off) ? part[tid - off] : 0;
    __syncthreads();
    part[tid] += v;
    __syncthreads();
  }
  int run = (tid == 0) ? 0 : part[tid - 1];
  for (int i = b; i < e; ++i) {
    rowptr[i] = run;
    fill[i] = run;
    run += deg[i];
  }
  if (b < N && e == N) rowptr[N] = run;
}

__global__ void __launch_bounds__(256) k_scatter(const int* __restrict__ src, const int* __restrict__ dst,
                                                 int* __restrict__ fill, int* __restrict__ srcs, int E) {
  int e = blockIdx.x * 256 + threadIdx.x;
  if (e >= E) return;
  int pos = atomicAdd(&fill[dst[e]], 1);
  srcs[pos] = src[e];
}

// ---------- fused edge phase: per-destination softmax + aggregation ----------
// one 64-lane wave per destination node; no atomics, no scratch memsets
template <int H>
__global__ void __launch_bounds__(64) k_edge_fused(const int* __restrict__ rowptr,
                                                   const int* __restrict__ srcs,
                                                   const float* __restrict__ es,
                                                   const float* __restrict__ ed,
                                                   const float* __restrict__ Wh,
                                                   float* __restrict__ agg) {
  const int t = blockIdx.x;
  const int lane = threadIdx.x;
  const int b0 = rowptr[t], b1 = rowptr[t + 1];
  const int deg = b1 - b0;
  float* aggp = agg + (size_t)t * D;
  if (deg == 0) {
    aggp[lane] = 0.f;
    aggp[lane + 64] = 0.f;
    return;
  }
  float edv[H];
#pragma unroll
  for (int h = 0; h < H; ++h) edv[h] = ed[t * H + h];
  // phase A1: running max per head
  float m[H];
#pragma unroll
  for (int h = 0; h < H; ++h) m[h] = -1e30f;
  for (int i = lane; i < deg; i += 64) {
    int s = srcs[b0 + i];
#pragma unroll
    for (int h = 0; h < H; ++h) {
      float v = es[s * H + h] + edv[h];
      v = v > 0.f ? v : 0.2f * v;
      m[h] = fmaxf(m[h], v);
    }
  }
#pragma unroll
  for (int h = 0; h < H; ++h) {
#pragma unroll
    for (int off = 32; off; off >>= 1) m[h] = fmaxf(m[h], __shfl_xor(m[h], off));
  }
  // phase A2: denominator per head
  float den[H];
#pragma unroll
  for (int h = 0; h < H; ++h) den[h] = 0.f;
  for (int i = lane; i < deg; i += 64) {
    int s = srcs[b0 + i];
#pragma unroll
    for (int h = 0; h < H; ++h) {
      float v = es[s * H + h] + edv[h];
      v = v > 0.f ? v : 0.2f * v;
      den[h] += __expf(v - m[h]);
    }
  }
#pragma unroll
  for (int h = 0; h < H; ++h) {
#pragma unroll
    for (int off = 32; off; off >>= 1) den[h] += __shfl_xor(den[h], off);
  }
  float rden[H];
#pragma unroll
  for (int h = 0; h < H; ++h) rden[h] = 1.f / den[h];
  // phase B: chunked alpha staging + gather-accumulate
  __shared__ float s_alpha[64][H];
  __shared__ int s_src[64];
  float acc0 = 0.f, acc1 = 0.f;
  for (int c0 = 0; c0 < deg; c0 += 64) {
    int ce = min(64, deg - c0);
    if (lane < ce) {
      int s = srcs[b0 + c0 + lane];
      s_src[lane] = s;
#pragma unroll
      for (int h = 0; h < H; ++h) {
        float v = es[s * H + h] + edv[h];
        v = v > 0.f ? v : 0.2f * v;
        s_alpha[lane][h] = __expf(v - m[h]) * rden[h];
      }
    }
    __syncthreads();
    for (int e = 0; e < ce; ++e) {
      int s = s_src[e];
      const float* wp = Wh + (size_t)s * H * D;
#pragma unroll
      for (int h = 0; h < H; ++h) {
        float a = s_alpha[e][h];
        acc0 += a * wp[h * D + lane];
        acc1 += a * wp[h * D + lane + 64];
      }
    }
    __syncthreads();
  }
  aggp[lane] = acc0 * (1.0f / H);
  aggp[lane + 64] = acc1 * (1.0f / H);
}

// ---------- layer-1 epilogue: h_out = elu(agg) ----------
__global__ void __launch_bounds__(256) k_elu(const float* __restrict__ agg, float* __restrict__ out, int n) {
  int i = blockIdx.x * 256 + threadIdx.x;
  if (i >= n) return;
  float x = agg[i];
  out[i] = x > 0.f ? x : expm1f(x);
}

// ---------- GRU epilogue: out = elu(agg); h_out = GRUCell(out, hin) ----------
__global__ void __launch_bounds__(128) k_gru(const float* __restrict__ agg, const float* __restrict__ hin,
                                             const float* __restrict__ WihT, const float* __restrict__ WhhT,
                                             const float* __restrict__ bih, const float* __restrict__ bhh,
                                             float* __restrict__ hout) {
  __shared__ float xs[8][D];
  __shared__ float hsm[8][D];
  const int n0 = blockIdx.x * 8;
  const int tid = threadIdx.x;  // 128
  for (int i = tid; i < 8 * D; i += 128) {
    int r = i >> 7, c = i & 127;
    float x = agg[(size_t)(n0 + r) * D + c];
    xs[r][c] = x > 0.f ? x : expm1f(x);
    hsm[r][c] = hin[(size_t)(n0 + r) * D + c];
  }
  __syncthreads();
  const int d = tid;
  float air[8] = {}, aiz[8] = {}, ain[8] = {}, ahr[8] = {}, ahz[8] = {}, ahn[8] = {};
  for (int k0 = 0; k0 < D; k0 += 4) {
    float wi0[4], wi1[4], wi2[4], wh0[4], wh1[4], wh2[4];
#pragma unroll
    for (int q = 0; q < 4; ++q) {
      wi0[q] = WihT[(k0 + q) * 384 + d];
      wi1[q] = WihT[(k0 + q) * 384 + 128 + d];
      wi2[q] = WihT[(k0 + q) * 384 + 256 + d];
      wh0[q] = WhhT[(k0 + q) * 384 + d];
      wh1[q] = WhhT[(k0 + q) * 384 + 128 + d];
      wh2[q] = WhhT[(k0 + q) * 384 + 256 + d];
    }
#pragma unroll
    for (int i = 0; i < 8; ++i) {
      float4 xv = *(const float4*)&xs[i][k0];
      float4 hv = *(const float4*)&hsm[i][k0];
      air[i] += xv.x * wi0[0] + xv.y * wi0[1] + xv.z * wi0[2] + xv.w * wi0[3];
      aiz[i] += xv.x * wi1[0] + xv.y * wi1[1] + xv.z * wi1[2] + xv.w * wi1[3];
      ain[i] += xv.x * wi2[0] + xv.y * wi2[1] + xv.z * wi2[2] + xv.w * wi2[3];
      ahr[i] += hv.x * wh0[0] + hv.y * wh0[1] + hv.z * wh0[2] + hv.w * wh0[3];
      ahz[i] += hv.x * wh1[0] + hv.y * wh1[1] + hv.z * wh1[2] + hv.w * wh1[3];
      ahn[i] += hv.x * wh2[0] + hv.y * wh2[1] + hv.z * wh2[2] + hv.w * wh2[3];
    }
  }
  const float bi0 = bih[d], bi1 = bih[128 + d], bi2 = bih[256 + d];
  const float bh0 = bhh[d], bh1 = bhh[128 + d], bh2 = bhh[256 + d];
#pragma unroll
  for (int i = 0; i < 8; ++i) {
    float r = sigmoidf_(air[i] + bi0 + ahr[i] + bh0);
    float z = sigmoidf_(aiz[i] + bi1 + ahz[i] + bh1);
    float nn = tanhf(ain[i] + bi2 + r * (ahn[i] + bh2));
    float hprev = hsm[i][d];
    hout[(size_t)(n0 + i) * D + d] = (1.f - z) * nn + z * hprev;
  }
}

// ---------- transpose [rows,cols] -> [cols,rows] ----------
__global__ void __launch_bounds__(256) k_transpose(const float* __restrict__ W, float* __restrict__ WT,
                                                   int rows, int cols) {
  int i = blockIdx.x * 256 + threadIdx.x;
  if (i >= rows * cols) return;
  int r = i / cols, c = i % cols;
  WT[c * rows + r] = W[i];
}

// ---------- final: out[n] = sigmoid(dot(h[n,:], W5) + b5) ----------
__global__ void __launch_bounds__(256) k_final(const float* __restrict__ h, const float* __restrict__ W5,
                                               const float* __restrict__ b5, float* __restrict__ out, int N) {
  int w = blockIdx.x * 4 + (threadIdx.x >> 6);
  int lane = threadIdx.x & 63;
  if (w >= N) return;
  float x = h[(size_t)w * D + lane] * W5[lane] + h[(size_t)w * D + lane + 64] * W5[lane + 64];
#pragma unroll
  for (int off = 32; off; off >>= 1) x += __shfl_down(x, off);
  if (lane == 0) out[w] = sigmoidf_(x + b5[0]);
}

// ---------- host-side one layer ----------
template <int H>
static void run_layer(const float* hin, const float* W, const float* a_s, const float* a_d,
                      const float* WihT, const float* WhhT, const float* bih, const float* bhh,
                      float* Wh, float* es, float* ed, float* agg, float* hout,
                      const int* rowptr, const int* srcs, int N, int E, hipStream_t stream) {
  dim3 g1(N / 16, H);
  k_gemm_wh<H><<<g1, 256, 0, stream>>>(hin, W, Wh);
  const int NH = N * H;
  k_es_ed<H><<<(NH + 3) / 4, 256, 0, stream>>>(Wh, a_s, a_d, es, ed, NH);
  k_edge_fused<H><<<N, 64, 0, stream>>>(rowptr, srcs, es, ed, Wh, agg);
  if (WihT) {
    k_gru<<<N / 8, 128, 0, stream>>>(agg, hin, WihT, WhhT, bih, bhh, hout);
  } else {
    k_elu<<<(N * D + 255) / 256, 256, 0, stream>>>(agg, hout, N * D);
  }
}

extern "C" void kernel_launch(void* const* d_in, const int* in_sizes, int n_in,
                              void* d_out, int out_size, void* d_ws, size_t ws_size,
                              hipStream_t stream) {
  const float* h0 = (const float*)d_in[0];
  const int* ei = (const int*)d_in[1];
  const float* W1 = (const float*)d_in[2];
  const float* as1 = (const float*)d_in[3];
  const float* ad1 = (const float*)d_in[4];
  const float* W2 = (const float*)d_in[5];
  const float* as2 = (const float*)d_in[6];
  const float* ad2 = (const float*)d_in[7];
  const float* W3 = (const float*)d_in[8];
  const float* as3 = (const float*)d_in[9];
  const float* ad3 = (const float*)d_in[10];
  const float* W4 = (const float*)d_in[11];
  const float* as4 = (const float*)d_in[12];
  const float* ad4 = (const float*)d_in[13];
  const float* Wih = (const float*)d_in[14];
  const float* Whh = (const float*)d_in[15];
  const float* bih = (const float*)d_in[16];
  const float* bhh = (const float*)d_in[17];
  const float* W5 = (const float*)d_in[18];
  const float* b5 = (const float*)d_in[19];

  const int N = in_sizes[0] / D;  // 20000
  const int E = in_sizes[1] / 2;  // 320000
  const int* src = ei;
  const int* dst = ei + E;

  // workspace layout (floats)
  float* ws = (float*)d_ws;
  float* Wh = ws;                       // N*4*D
  float* agg = Wh + (size_t)N * 4 * D;  // N*D
  float* hA = agg + (size_t)N * D;      // N*D
  float* hB = hA + (size_t)N * D;       // N*D
  float* es = hB + (size_t)N * D;       // N*4
  float* ed = es + (size_t)N * 4;       // N*4
  float* WihT = ed + (size_t)N * 4;     // 128*384
  float* WhhT = WihT + 384 * 128;       // 128*384
  // int scratch (CSR)
  int* deg = (int*)(WhhT + 384 * 128);  // N
  int* rowptr = deg + N;                // N+1
  int* fill = rowptr + N + 1;           // N
  int* srcs = fill + N;                 // E

  // ---- CSR build (once; graph shared by all 4 layers) ----
  hipMemsetAsync(deg, 0, (size_t)N * 4, stream);
  k_hist<<<(E + 255) / 256, 256, 0, stream>>>(dst, deg, E);
  k_scan<<<1, 1024, 0, stream>>>(deg, rowptr, fill, N);
  k_scatter<<<(E + 255) / 256, 256, 0, stream>>>(src, dst, fill, srcs, E);

  // transpose GRU weights once
  k_transpose<<<(384 * 128 + 255) / 256, 256, 0, stream>>>(Wih, WihT, 384, 128);
  k_transpose<<<(384 * 128 + 255) / 256, 256, 0, stream>>>(Whh, WhhT, 384, 128);

  // layer 1: H=4, no GRU
  run_layer<4>(h0, W1, as1, ad1, nullptr, nullptr, nullptr, nullptr,
               Wh, es, ed, agg, hA, rowptr, srcs, N, E, stream);
  // layer 2: H=4, GRU
  run_layer<4>(hA, W2, as2, ad2, WihT, WhhT, bih, bhh,
               Wh, es, ed, agg, hB, rowptr, srcs, N, E, stream);
  // layer 3: H=4, GRU
  run_layer<4>(hB, W3, as3, ad3, WihT, WhhT, bih, bhh,
               Wh, es, ed, agg, hA, rowptr, srcs, N, E, stream);
  // layer 4: H=1, GRU
  run_layer<1>(hA, W4, as4, ad4, WihT, WhhT, bih, bhh,
               Wh, es, ed, agg, hB, rowptr, srcs, N, E, stream);

  // output head
  k_final<<<(N + 3) / 4, 256, 0, stream>>>(hB, W5, b5, (float*)d_out, N);
}

// Round 3
// 420.825 us; speedup vs baseline: 3.8889x; 2.2097x over previous
//
#include <hip/hip_runtime.h>
#include <math.h>

#define D 128

typedef __attribute__((ext_vector_type(8))) short bf16x8;
typedef __attribute__((ext_vector_type(4))) float f32x4;

__device__ __forceinline__ float sigmoidf_(float x) { return 1.f / (1.f + __expf(-x)); }
__device__ __forceinline__ float bf2f(unsigned short u) { return __uint_as_float(((unsigned)u) << 16); }
__device__ __forceinline__ unsigned short f2b(float f) {
  unsigned u = __float_as_uint(f);
  return (unsigned short)((u + 0x7fffu + ((u >> 16) & 1u)) >> 16);  // RNE
}

// ---------- fp32 -> bf16 convert ----------
__global__ void __launch_bounds__(256) k_f2b(const float* __restrict__ in,
                                             unsigned short* __restrict__ out, int n) {
  int i = blockIdx.x * 256 + threadIdx.x;
  if (i < n) out[i] = f2b(in[i]);
}

// ---------- pack W[h,k,d] -> MFMA B-fragment layout, B[k][h*128+d] ----------
// Bp linear index i = ((kb*(NCOLS/16)+db)*64 + lane)*8 + j
// holds B[kb*32 + 8*(lane>>4) + j][db*16 + (lane&15)]
template <int NCOLS>
__global__ void __launch_bounds__(256) k_pack_w(const float* __restrict__ W,
                                                unsigned short* __restrict__ Bp) {
  int i = blockIdx.x * 256 + threadIdx.x;
  if (i >= 128 * NCOLS) return;
  int j = i & 7;
  int lane = (i >> 3) & 63;
  int rest = i >> 9;  // kb*(NCOLS/16)+db
  int db = rest % (NCOLS / 16);
  int kb = rest / (NCOLS / 16);
  int k = kb * 32 + ((lane >> 4) << 3) + j;
  int col = db * 16 + (lane & 15);
  int h = col >> 7, d = col & 127;
  Bp[i] = f2b(W[((size_t)h * 128 + k) * 128 + d]);
}

// ---------- pack GRU weight S[384][128] (torch GRUCell layout) as B[k][col]=S[col][k] ----------
__global__ void __launch_bounds__(256) k_pack_gru(const float* __restrict__ S,
                                                  unsigned short* __restrict__ Bp) {
  int i = blockIdx.x * 256 + threadIdx.x;
  if (i >= 128 * 384) return;
  int j = i & 7;
  int lane = (i >> 3) & 63;
  int rest = i >> 9;  // kb*24+db
  int db = rest % 24;
  int kb = rest / 24;
  int k = kb * 32 + ((lane >> 4) << 3) + j;
  int col = db * 16 + (lane & 15);
  Bp[i] = f2b(S[(size_t)col * 128 + k]);
}

// ---------- MFMA GEMM: Whb[n][col] = sum_k hb[n][k] * B[k][col] ----------
template <int NCOLS>  // 512 (H=4) or 128 (H=1)
__global__ void __launch_bounds__(256) k_wh_mfma(const unsigned short* __restrict__ hb,
                                                 const unsigned short* __restrict__ Bp,
                                                 unsigned short* __restrict__ Whb) {
  const int n0 = blockIdx.x * 16;
  const int w = threadIdx.x >> 6;
  const int lane = threadIdx.x & 63;
  constexpr int TPW = NCOLS / 64;  // 16-col tiles per wave
  f32x4 acc[TPW];
#pragma unroll
  for (int t = 0; t < TPW; ++t) acc[t] = (f32x4)0.f;
  const int arow = n0 + (lane & 15);
  const int koff = (lane >> 4) << 3;
#pragma unroll
  for (int kb = 0; kb < 4; ++kb) {
    bf16x8 a = *(const bf16x8*)&hb[(size_t)arow * 128 + kb * 32 + koff];
#pragma unroll
    for (int t = 0; t < TPW; ++t) {
      const int ct = w * TPW + t;
      bf16x8 b = *(const bf16x8*)&Bp[((size_t)(kb * (NCOLS / 16) + ct) * 64 + lane) * 8];
      acc[t] = __builtin_amdgcn_mfma_f32_16x16x32_bf16(a, b, acc[t], 0, 0, 0);
    }
  }
  const int rbase = n0 + ((lane >> 4) << 2);
#pragma unroll
  for (int t = 0; t < TPW; ++t) {
    const int col = (w * TPW + t) * 16 + (lane & 15);
#pragma unroll
    for (int i = 0; i < 4; ++i) {
      Whb[(size_t)(rbase + i) * NCOLS + col] = f2b(acc[t][i]);
    }
  }
}

// ---------- es[n,h] = dot(Wh[n,h,:], a_src[h,:]), ed likewise ----------
template <int H>
__global__ void __launch_bounds__(256) k_es_ed(const unsigned short* __restrict__ Whb,
                                               const float* __restrict__ a_src,
                                               const float* __restrict__ a_dst,
                                               float* __restrict__ es,
                                               float* __restrict__ ed, int NH) {
  int w = blockIdx.x * 4 + (threadIdx.x >> 6);
  int lane = threadIdx.x & 63;
  if (w >= NH) return;
  int hh = w % H;
  const unsigned short* row = Whb + (size_t)w * D;
  float x0 = bf2f(row[lane]), x1 = bf2f(row[lane + 64]);
  float s = x0 * a_src[hh * D + lane] + x1 * a_src[hh * D + lane + 64];
  float t = x0 * a_dst[hh * D + lane] + x1 * a_dst[hh * D + lane + 64];
#pragma unroll
  for (int off = 32; off; off >>= 1) {
    s += __shfl_down(s, off);
    t += __shfl_down(t, off);
  }
  if (lane == 0) {
    es[w] = s;
    ed[w] = t;
  }
}

// ---------- CSR build ----------
__global__ void __launch_bounds__(256) k_hist(const int* __restrict__ dst, int* __restrict__ deg, int E) {
  int e = blockIdx.x * 256 + threadIdx.x;
  if (e < E) atomicAdd(&deg[dst[e]], 1);
}

__global__ void __launch_bounds__(1024) k_scan(const int* __restrict__ deg, int* __restrict__ rowptr,
                                               int* __restrict__ fill, int N) {
  __shared__ int part[1024];
  const int tid = threadIdx.x;
  const int chunk = (N + 1023) / 1024;
  const int b = tid * chunk;
  const int e = min(N, b + chunk);
  int s = 0;
  for (int i = b; i < e; ++i) s += deg[i];
  part[tid] = s;
  __syncthreads();
  for (int off = 1; off < 1024; off <<= 1) {
    int v = (tid >= off) ? part[tid - off] : 0;
    __syncthreads();
    part[tid] += v;
    __syncthreads();
  }
  int run = (tid == 0) ? 0 : part[tid - 1];
  for (int i = b; i < e; ++i) {
    rowptr[i] = run;
    fill[i] = run;
    run += deg[i];
  }
  if (b < N && e == N) rowptr[N] = run;
}

__global__ void __launch_bounds__(256) k_scatter(const int* __restrict__ src, const int* __restrict__ dst,
                                                 int* __restrict__ fill, int* __restrict__ srcs, int E) {
  int e = blockIdx.x * 256 + threadIdx.x;
  if (e >= E) return;
  int pos = atomicAdd(&fill[dst[e]], 1);
  srcs[pos] = src[e];
}

// ---------- fused edge phase: per-destination softmax + aggregation ----------
template <int H>
__global__ void __launch_bounds__(64) k_edge_fused(const int* __restrict__ rowptr,
                                                   const int* __restrict__ srcs,
                                                   const float* __restrict__ es,
                                                   const float* __restrict__ ed,
                                                   const unsigned short* __restrict__ Whb,
                                                   float* __restrict__ agg) {
  const int t = blockIdx.x;
  const int lane = threadIdx.x;
  const int b0 = rowptr[t], b1 = rowptr[t + 1];
  const int deg = b1 - b0;
  float* aggp = agg + (size_t)t * D;
  if (deg == 0) {
    ((float2*)aggp)[lane] = make_float2(0.f, 0.f);
    return;
  }
  float edv[H];
#pragma unroll
  for (int h = 0; h < H; ++h) edv[h] = ed[t * H + h];
  // phase A1: max per head
  float m[H];
#pragma unroll
  for (int h = 0; h < H; ++h) m[h] = -1e30f;
  for (int i = lane; i < deg; i += 64) {
    int s = srcs[b0 + i];
    if constexpr (H == 4) {
      float4 ev = *(const float4*)&es[s * 4];
      float vv[4] = {ev.x, ev.y, ev.z, ev.w};
#pragma unroll
      for (int h = 0; h < 4; ++h) {
        float v = vv[h] + edv[h];
        v = v > 0.f ? v : 0.2f * v;
        m[h] = fmaxf(m[h], v);
      }
    } else {
      float v = es[s] + edv[0];
      v = v > 0.f ? v : 0.2f * v;
      m[0] = fmaxf(m[0], v);
    }
  }
#pragma unroll
  for (int h = 0; h < H; ++h) {
#pragma unroll
    for (int off = 32; off; off >>= 1) m[h] = fmaxf(m[h], __shfl_xor(m[h], off));
  }
  // phase A2: denominator
  float den[H];
#pragma unroll
  for (int h = 0; h < H; ++h) den[h] = 0.f;
  for (int i = lane; i < deg; i += 64) {
    int s = srcs[b0 + i];
    if constexpr (H == 4) {
      float4 ev = *(const float4*)&es[s * 4];
      float vv[4] = {ev.x, ev.y, ev.z, ev.w};
#pragma unroll
      for (int h = 0; h < 4; ++h) {
        float v = vv[h] + edv[h];
        v = v > 0.f ? v : 0.2f * v;
        den[h] += __expf(v - m[h]);
      }
    } else {
      float v = es[s] + edv[0];
      v = v > 0.f ? v : 0.2f * v;
      den[0] += __expf(v - m[0]);
    }
  }
#pragma unroll
  for (int h = 0; h < H; ++h) {
#pragma unroll
    for (int off = 32; off; off >>= 1) den[h] += __shfl_xor(den[h], off);
  }
  float rden[H];
#pragma unroll
  for (int h = 0; h < H; ++h) rden[h] = 1.f / den[h];
  // phase B: chunked alpha staging + gather-accumulate (cols 2*lane, 2*lane+1)
  __shared__ float s_alpha[64][H];
  __shared__ int s_src[64];
  float acc0 = 0.f, acc1 = 0.f;
  for (int c0 = 0; c0 < deg; c0 += 64) {
    int ce = min(64, deg - c0);
    if (lane < ce) {
      int s = srcs[b0 + c0 + lane];
      s_src[lane] = s;
      if constexpr (H == 4) {
        float4 ev = *(const float4*)&es[s * 4];
        float vv[4] = {ev.x, ev.y, ev.z, ev.w};
#pragma unroll
        for (int h = 0; h < 4; ++h) {
          float v = vv[h] + edv[h];
          v = v > 0.f ? v : 0.2f * v;
          s_alpha[lane][h] = __expf(v - m[h]) * rden[h];
        }
      } else {
        float v = es[s] + edv[0];
        v = v > 0.f ? v : 0.2f * v;
        s_alpha[lane][0] = __expf(v - m[0]) * rden[0];
      }
    }
    __syncthreads();
    for (int e = 0; e < ce; ++e) {
      int s = s_src[e];
      const unsigned short* wp = Whb + (size_t)s * (H * D);
#pragma unroll
      for (int h = 0; h < H; ++h) {
        float a = s_alpha[e][h];
        unsigned v = *(const unsigned*)&wp[h * D + 2 * lane];
        acc0 += a * bf2f((unsigned short)(v & 0xffffu));
        acc1 += a * bf2f((unsigned short)(v >> 16));
      }
    }
    __syncthreads();
  }
  ((float2*)aggp)[lane] = make_float2(acc0 * (1.0f / H), acc1 * (1.0f / H));
}

// ---------- layer-1 epilogue: h_out = elu(agg) (f32 + bf16) ----------
__global__ void __launch_bounds__(256) k_elu2(const float* __restrict__ agg, float* __restrict__ out,
                                              unsigned short* __restrict__ outb, int n) {
  int i = blockIdx.x * 256 + threadIdx.x;
  if (i >= n) return;
  float x = agg[i];
  float y = x > 0.f ? x : expm1f(x);
  out[i] = y;
  outb[i] = f2b(y);
}

// ---------- fused GRU: x=elu(agg); gi=x@Wih^T; gh=h@Whh^T; gate epilogue ----------
__global__ void __launch_bounds__(256) k_gru_mfma(const float* __restrict__ agg,
                                                  const float* __restrict__ hf,
                                                  const unsigned short* __restrict__ hb,
                                                  const unsigned short* __restrict__ Bih,
                                                  const unsigned short* __restrict__ Bhh,
                                                  const float* __restrict__ bih,
                                                  const float* __restrict__ bhh,
                                                  float* __restrict__ houtf,
                                                  unsigned short* __restrict__ houtb) {
  const int n0 = blockIdx.x * 16;
  const int w = threadIdx.x >> 6;
  const int lane = threadIdx.x & 63;
  f32x4 ai[3][2], ah[3][2];
#pragma unroll
  for (int p = 0; p < 3; ++p)
#pragma unroll
    for (int t = 0; t < 2; ++t) {
      ai[p][t] = (f32x4)0.f;
      ah[p][t] = (f32x4)0.f;
    }
  const int arow = n0 + (lane & 15);
  const int koff = (lane >> 4) << 3;
#pragma unroll
  for (int kb = 0; kb < 4; ++kb) {
    const size_t abase = (size_t)arow * 128 + kb * 32 + koff;
    float4 a0 = *(const float4*)&agg[abase];
    float4 a1 = *(const float4*)&agg[abase + 4];
    bf16x8 ax;
    {
      float v0 = a0.x > 0.f ? a0.x : expm1f(a0.x);
      float v1 = a0.y > 0.f ? a0.y : expm1f(a0.y);
      float v2 = a0.z > 0.f ? a0.z : expm1f(a0.z);
      float v3 = a0.w > 0.f ? a0.w : expm1f(a0.w);
      float v4 = a1.x > 0.f ? a1.x : expm1f(a1.x);
      float v5 = a1.y > 0.f ? a1.y : expm1f(a1.y);
      float v6 = a1.z > 0.f ? a1.z : expm1f(a1.z);
      float v7 = a1.w > 0.f ? a1.w : expm1f(a1.w);
      ax[0] = (short)f2b(v0); ax[1] = (short)f2b(v1);
      ax[2] = (short)f2b(v2); ax[3] = (short)f2b(v3);
      ax[4] = (short)f2b(v4); ax[5] = (short)f2b(v5);
      ax[6] = (short)f2b(v6); ax[7] = (short)f2b(v7);
    }
    bf16x8 ahr = *(const bf16x8*)&hb[abase];
#pragma unroll
    for (int p = 0; p < 3; ++p) {
#pragma unroll
      for (int t = 0; t < 2; ++t) {
        const int ct = p * 8 + w * 2 + t;
        bf16x8 bi = *(const bf16x8*)&Bih[((size_t)(kb * 24 + ct) * 64 + lane) * 8];
        ai[p][t] = __builtin_amdgcn_mfma_f32_16x16x32_bf16(ax, bi, ai[p][t], 0, 0, 0);
        bf16x8 bh = *(const bf16x8*)&Bhh[((size_t)(kb * 24 + ct) * 64 + lane) * 8];
        ah[p][t] = __builtin_amdgcn_mfma_f32_16x16x32_bf16(ahr, bh, ah[p][t], 0, 0, 0);
      }
    }
  }
  const int rbase = n0 + ((lane >> 4) << 2);
#pragma unroll
  for (int t = 0; t < 2; ++t) {
    const int j = (w * 2 + t) * 16 + (lane & 15);
    const float bir = bih[j], biz = bih[128 + j], bin = bih[256 + j];
    const float bhr = bhh[j], bhz = bhh[128 + j], bhn = bhh[256 + j];
#pragma unroll
    for (int i = 0; i < 4; ++i) {
      const int row = rbase + i;
      float r = sigmoidf_(ai[0][t][i] + bir + ah[0][t][i] + bhr);
      float z = sigmoidf_(ai[1][t][i] + biz + ah[1][t][i] + bhz);
      float nn = tanhf(ai[2][t][i] + bin + r * (ah[2][t][i] + bhn));
      float hp = hf[(size_t)row * 128 + j];
      float o = (1.f - z) * nn + z * hp;
      houtf[(size_t)row * 128 + j] = o;
      houtb[(size_t)row * 128 + j] = f2b(o);
    }
  }
}

// ---------- final: out[n] = sigmoid(dot(h[n,:], W5) + b5) ----------
__global__ void __launch_bounds__(256) k_final(const float* __restrict__ h, const float* __restrict__ W5,
                                               const float* __restrict__ b5, float* __restrict__ out, int N) {
  int w = blockIdx.x * 4 + (threadIdx.x >> 6);
  int lane = threadIdx.x & 63;
  if (w >= N) return;
  float x = h[(size_t)w * D + lane] * W5[lane] + h[(size_t)w * D + lane + 64] * W5[lane + 64];
#pragma unroll
  for (int off = 32; off; off >>= 1) x += __shfl_down(x, off);
  if (lane == 0) out[w] = sigmoidf_(x + b5[0]);
}

extern "C" void kernel_launch(void* const* d_in, const int* in_sizes, int n_in,
                              void* d_out, int out_size, void* d_ws, size_t ws_size,
                              hipStream_t stream) {
  const float* h0 = (const float*)d_in[0];
  const int* ei = (const int*)d_in[1];
  const float* W1 = (const float*)d_in[2];
  const float* as1 = (const float*)d_in[3];
  const float* ad1 = (const float*)d_in[4];
  const float* W2 = (const float*)d_in[5];
  const float* as2 = (const float*)d_in[6];
  const float* ad2 = (const float*)d_in[7];
  const float* W3 = (const float*)d_in[8];
  const float* as3 = (const float*)d_in[9];
  const float* ad3 = (const float*)d_in[10];
  const float* W4 = (const float*)d_in[11];
  const float* as4 = (const float*)d_in[12];
  const float* ad4 = (const float*)d_in[13];
  const float* Wih = (const float*)d_in[14];
  const float* Whh = (const float*)d_in[15];
  const float* bih = (const float*)d_in[16];
  const float* bhh = (const float*)d_in[17];
  const float* W5 = (const float*)d_in[18];
  const float* b5 = (const float*)d_in[19];

  const int N = in_sizes[0] / D;  // 20000
  const int E = in_sizes[1] / 2;  // 320000
  const int* src = ei;
  const int* dst = ei + E;

  // ---- workspace layout ----
  float* ws = (float*)d_ws;
  unsigned short* Whb = (unsigned short*)ws;          // N*512 ushorts (N*256 floats)
  float* agg = ws + (size_t)N * 256;                  // N*128
  float* hA = agg + (size_t)N * 128;                  // N*128
  float* hB = hA + (size_t)N * 128;                   // N*128
  float* es = hB + (size_t)N * 128;                   // N*4
  float* ed = es + (size_t)N * 4;                     // N*4
  unsigned short* h0b = (unsigned short*)(ed + (size_t)N * 4);  // N*128 us = N*64 f
  unsigned short* hAb = h0b + (size_t)N * 128;        // N*128 us
  unsigned short* hBb = hAb + (size_t)N * 128;        // N*128 us
  unsigned short* BpW = hBb + (size_t)N * 128;        // 128*512 us
  unsigned short* Bih = BpW + 128 * 512;              // 128*384 us
  unsigned short* Bhh = Bih + 128 * 384;              // 128*384 us
  int* deg = (int*)(Bhh + 128 * 384);                 // N
  int* rowptr = deg + N;                              // N+1
  int* fill = rowptr + N + 1;                         // N
  int* srcs = fill + N;                               // E

  // ---- one-time prep ----
  k_f2b<<<(N * 128 + 255) / 256, 256, 0, stream>>>(h0, h0b, N * 128);
  k_pack_gru<<<(128 * 384 + 255) / 256, 256, 0, stream>>>(Wih, Bih);
  k_pack_gru<<<(128 * 384 + 255) / 256, 256, 0, stream>>>(Whh, Bhh);
  hipMemsetAsync(deg, 0, (size_t)N * 4, stream);
  k_hist<<<(E + 255) / 256, 256, 0, stream>>>(dst, deg, E);
  k_scan<<<1, 1024, 0, stream>>>(deg, rowptr, fill, N);
  k_scatter<<<(E + 255) / 256, 256, 0, stream>>>(src, dst, fill, srcs, E);

  const int NH4 = N * 4;
  // ---- layer 1: H=4, no GRU ----
  k_pack_w<512><<<(128 * 512 + 255) / 256, 256, 0, stream>>>(W1, BpW);
  k_wh_mfma<512><<<N / 16, 256, 0, stream>>>(h0b, BpW, Whb);
  k_es_ed<4><<<(NH4 + 3) / 4, 256, 0, stream>>>(Whb, as1, ad1, es, ed, NH4);
  k_edge_fused<4><<<N, 64, 0, stream>>>(rowptr, srcs, es, ed, Whb, agg);
  k_elu2<<<(N * 128 + 255) / 256, 256, 0, stream>>>(agg, hA, hAb, N * 128);
  // ---- layer 2: H=4, GRU ----
  k_pack_w<512><<<(128 * 512 + 255) / 256, 256, 0, stream>>>(W2, BpW);
  k_wh_mfma<512><<<N / 16, 256, 0, stream>>>(hAb, BpW, Whb);
  k_es_ed<4><<<(NH4 + 3) / 4, 256, 0, stream>>>(Whb, as2, ad2, es, ed, NH4);
  k_edge_fused<4><<<N, 64, 0, stream>>>(rowptr, srcs, es, ed, Whb, agg);
  k_gru_mfma<<<N / 16, 256, 0, stream>>>(agg, hA, hAb, Bih, Bhh, bih, bhh, hB, hBb);
  // ---- layer 3: H=4, GRU ----
  k_pack_w<512><<<(128 * 512 + 255) / 256, 256, 0, stream>>>(W3, BpW);
  k_wh_mfma<512><<<N / 16, 256, 0, stream>>>(hBb, BpW, Whb);
  k_es_ed<4><<<(NH4 + 3) / 4, 256, 0, stream>>>(Whb, as3, ad3, es, ed, NH4);
  k_edge_fused<4><<<N, 64, 0, stream>>>(rowptr, srcs, es, ed, Whb, agg);
  k_gru_mfma<<<N / 16, 256, 0, stream>>>(agg, hB, hBb, Bih, Bhh, bih, bhh, hA, hAb);
  // ---- layer 4: H=1, GRU ----
  k_pack_w<128><<<(128 * 128 + 255) / 256, 256, 0, stream>>>(W4, BpW);
  k_wh_mfma<128><<<N / 16, 256, 0, stream>>>(hAb, BpW, Whb);
  k_es_ed<1><<<(N + 3) / 4, 256, 0, stream>>>(Whb, as4, ad4, es, ed, N);
  k_edge_fused<1><<<N, 64, 0, stream>>>(rowptr, srcs, es, ed, Whb, agg);
  k_gru_mfma<<<N / 16, 256, 0, stream>>>(agg, hA, hAb, Bih, Bhh, bih, bhh, hB, hBb);

  // ---- output head ----
  k_final<<<(N + 3) / 4, 256, 0, stream>>>(hB, W5, b5, (float*)d_out, N);
}

// Round 4
// 416.738 us; speedup vs baseline: 3.9271x; 1.0098x over previous
//
#include <hip/hip_runtime.h>
#include <math.h>

#define D 128

typedef __attribute__((ext_vector_type(8))) short bf16x8;
typedef __attribute__((ext_vector_type(4))) float f32x4;

__device__ __forceinline__ float sigmoidf_(float x) { return 1.f / (1.f + __expf(-x)); }
__device__ __forceinline__ float bf2f(unsigned short u) { return __uint_as_float(((unsigned)u) << 16); }
__device__ __forceinline__ unsigned short f2b(float f) {
  unsigned u = __float_as_uint(f);
  return (unsigned short)((u + 0x7fffu + ((u >> 16) & 1u)) >> 16);  // RNE
}

// ---------- fp32 -> bf16 convert ----------
__global__ void __launch_bounds__(256) k_f2b(const float* __restrict__ in,
                                             unsigned short* __restrict__ out, int n) {
  int i = blockIdx.x * 256 + threadIdx.x;
  if (i < n) out[i] = f2b(in[i]);
}

// ---------- pack W[h,k,d] -> MFMA B-fragment layout ----------
template <int NCOLS>
__global__ void __launch_bounds__(256) k_pack_w(const float* __restrict__ W,
                                                unsigned short* __restrict__ Bp) {
  int i = blockIdx.x * 256 + threadIdx.x;
  if (i >= 128 * NCOLS) return;
  int j = i & 7;
  int lane = (i >> 3) & 63;
  int rest = i >> 9;  // kb*(NCOLS/16)+db
  int db = rest % (NCOLS / 16);
  int kb = rest / (NCOLS / 16);
  int k = kb * 32 + ((lane >> 4) << 3) + j;
  int col = db * 16 + (lane & 15);
  int h = col >> 7, d = col & 127;
  Bp[i] = f2b(W[((size_t)h * 128 + k) * 128 + d]);
}

// ---------- pack GRU weight S[384][128] as B[k][col]=S[col][k] ----------
__global__ void __launch_bounds__(256) k_pack_gru(const float* __restrict__ S,
                                                  unsigned short* __restrict__ Bp) {
  int i = blockIdx.x * 256 + threadIdx.x;
  if (i >= 128 * 384) return;
  int j = i & 7;
  int lane = (i >> 3) & 63;
  int rest = i >> 9;  // kb*24+db
  int db = rest % 24;
  int kb = rest / 24;
  int k = kb * 32 + ((lane >> 4) << 3) + j;
  int col = db * 16 + (lane & 15);
  Bp[i] = f2b(S[(size_t)col * 128 + k]);
}

// ---------- MFMA GEMM: 32-row tiles; optional fused es/ed epilogue (NCOLS=512) ----------
template <int NCOLS, bool FUSE>
__global__ void __launch_bounds__(256) k_wh_mfma(const unsigned short* __restrict__ hb,
                                                 const unsigned short* __restrict__ Bp,
                                                 unsigned short* __restrict__ Whb,
                                                 const float* __restrict__ a_src,
                                                 const float* __restrict__ a_dst,
                                                 float* __restrict__ es,
                                                 float* __restrict__ ed) {
  const int n0 = blockIdx.x * 32;
  const int w = threadIdx.x >> 6;
  const int lane = threadIdx.x & 63;
  const int r = lane & 15, g = lane >> 4;
  constexpr int TPW = NCOLS / 64;
  f32x4 acc[2][TPW];
#pragma unroll
  for (int m = 0; m < 2; ++m)
#pragma unroll
    for (int t = 0; t < TPW; ++t) acc[m][t] = (f32x4)0.f;
  const int koff = g << 3;
#pragma unroll
  for (int kb = 0; kb < 4; ++kb) {
    bf16x8 a0 = *(const bf16x8*)&hb[(size_t)(n0 + r) * 128 + kb * 32 + koff];
    bf16x8 a1 = *(const bf16x8*)&hb[(size_t)(n0 + 16 + r) * 128 + kb * 32 + koff];
#pragma unroll
    for (int t = 0; t < TPW; ++t) {
      const int ct = w * TPW + t;
      bf16x8 b = *(const bf16x8*)&Bp[((size_t)(kb * (NCOLS / 16) + ct) * 64 + lane) * 8];
      acc[0][t] = __builtin_amdgcn_mfma_f32_16x16x32_bf16(a0, b, acc[0][t], 0, 0, 0);
      acc[1][t] = __builtin_amdgcn_mfma_f32_16x16x32_bf16(a1, b, acc[1][t], 0, 0, 0);
    }
  }
#pragma unroll
  for (int m = 0; m < 2; ++m) {
    const int rbase = n0 + m * 16 + g * 4;
#pragma unroll
    for (int t = 0; t < TPW; ++t) {
      const int col = (w * TPW + t) * 16 + r;
#pragma unroll
      for (int i = 0; i < 4; ++i) {
        Whb[(size_t)(rbase + i) * NCOLS + col] = f2b(acc[m][t][i]);
      }
    }
  }
  if constexpr (FUSE) {
    // head = w; d = t*16 + r
    float av[TPW], bv[TPW];
#pragma unroll
    for (int t = 0; t < TPW; ++t) {
      av[t] = a_src[w * 128 + t * 16 + r];
      bv[t] = a_dst[w * 128 + t * 16 + r];
    }
#pragma unroll
    for (int m = 0; m < 2; ++m) {
      float sp[4] = {}, dp[4] = {};
#pragma unroll
      for (int t = 0; t < TPW; ++t)
#pragma unroll
        for (int i = 0; i < 4; ++i) {
          sp[i] += acc[m][t][i] * av[t];
          dp[i] += acc[m][t][i] * bv[t];
        }
#pragma unroll
      for (int off = 1; off < 16; off <<= 1)
#pragma unroll
        for (int i = 0; i < 4; ++i) {
          sp[i] += __shfl_xor(sp[i], off);
          dp[i] += __shfl_xor(dp[i], off);
        }
      if (r == 0) {
        const int rbase = n0 + m * 16 + g * 4;
#pragma unroll
        for (int i = 0; i < 4; ++i) {
          es[(size_t)(rbase + i) * 4 + w] = sp[i];
          ed[(size_t)(rbase + i) * 4 + w] = dp[i];
        }
      }
    }
  }
}

// ---------- es/ed for H=1 (layer 4) ----------
__global__ void __launch_bounds__(256) k_es_ed1(const unsigned short* __restrict__ Whb,
                                                const float* __restrict__ a_src,
                                                const float* __restrict__ a_dst,
                                                float* __restrict__ es,
                                                float* __restrict__ ed, int N) {
  int w = blockIdx.x * 4 + (threadIdx.x >> 6);
  int lane = threadIdx.x & 63;
  if (w >= N) return;
  const unsigned short* row = Whb + (size_t)w * D;
  float x0 = bf2f(row[lane]), x1 = bf2f(row[lane + 64]);
  float s = x0 * a_src[lane] + x1 * a_src[lane + 64];
  float t = x0 * a_dst[lane] + x1 * a_dst[lane + 64];
#pragma unroll
  for (int off = 32; off; off >>= 1) {
    s += __shfl_down(s, off);
    t += __shfl_down(t, off);
  }
  if (lane == 0) {
    es[w] = s;
    ed[w] = t;
  }
}

// ---------- CSR build ----------
__global__ void __launch_bounds__(256) k_hist(const int* __restrict__ dst, int* __restrict__ deg, int E) {
  int e = blockIdx.x * 256 + threadIdx.x;
  if (e < E) atomicAdd(&deg[dst[e]], 1);
}

__global__ void __launch_bounds__(1024) k_scan(const int* __restrict__ deg, int* __restrict__ rowptr,
                                               int* __restrict__ fill, int N) {
  __shared__ int part[1024];
  const int tid = threadIdx.x;
  const int chunk = (N + 1023) / 1024;
  const int b = tid * chunk;
  const int e = min(N, b + chunk);
  int s = 0;
  for (int i = b; i < e; ++i) s += deg[i];
  part[tid] = s;
  __syncthreads();
  for (int off = 1; off < 1024; off <<= 1) {
    int v = (tid >= off) ? part[tid - off] : 0;
    __syncthreads();
    part[tid] += v;
    __syncthreads();
  }
  int run = (tid == 0) ? 0 : part[tid - 1];
  for (int i = b; i < e; ++i) {
    rowptr[i] = run;
    fill[i] = run;
    run += deg[i];
  }
  if (b < N && e == N) rowptr[N] = run;
}

__global__ void __launch_bounds__(256) k_scatter(const int* __restrict__ src, const int* __restrict__ dst,
                                                 int* __restrict__ fill, int* __restrict__ srcs, int E) {
  int e = blockIdx.x * 256 + threadIdx.x;
  if (e >= E) return;
  int pos = atomicAdd(&fill[dst[e]], 1);
  srcs[pos] = src[e];
}

// ---------- fused edge phase v2: wave-per-node, register-staged, no LDS/barriers ----------
// EPI=0: write agg f32; EPI=1: write elu(agg) as f32 + bf16
template <int H, int EPI>
__global__ void __launch_bounds__(256) k_edge_fused(const int* __restrict__ rowptr,
                                                    const int* __restrict__ srcs,
                                                    const float* __restrict__ es,
                                                    const float* __restrict__ ed,
                                                    const unsigned short* __restrict__ Whb,
                                                    float* __restrict__ outf,
                                                    unsigned short* __restrict__ outb,
                                                    int N) {
  const int t = blockIdx.x * 4 + (threadIdx.x >> 6);
  if (t >= N) return;
  const int lane = threadIdx.x & 63;
  const int b0 = rowptr[t];
  const int deg = rowptr[t + 1] - b0;
  if (deg == 0) {
    ((float2*)(outf + (size_t)t * D))[lane] = make_float2(0.f, 0.f);
    if constexpr (EPI == 1) ((unsigned*)(outb + (size_t)t * D))[lane] = 0u;
    return;
  }
  float edv[H];
#pragma unroll
  for (int h = 0; h < H; ++h) edv[h] = ed[t * H + h];
  // ---- phase A: single online-softmax pass; keep first-64 edge state in regs ----
  float m[H], den[H], vreg[H];
  int sreg = 0;
#pragma unroll
  for (int h = 0; h < H; ++h) {
    m[h] = -1e30f;
    den[h] = 0.f;
    vreg[h] = -1e30f;
  }
  for (int i = lane; i < deg; i += 64) {
    int s = srcs[b0 + i];
    float vv[H];
    if constexpr (H == 4) {
      float4 ev = *(const float4*)&es[(size_t)s * 4];
      vv[0] = ev.x + edv[0];
      vv[1] = ev.y + edv[1];
      vv[2] = ev.z + edv[2];
      vv[3] = ev.w + edv[3];
    } else {
      vv[0] = es[s] + edv[0];
    }
#pragma unroll
    for (int h = 0; h < H; ++h) {
      float v = vv[h];
      v = v > 0.f ? v : 0.2f * v;
      vv[h] = v;
      float nm = fmaxf(m[h], v);
      den[h] = den[h] * __expf(m[h] - nm) + __expf(v - nm);
      m[h] = nm;
    }
    if (i == lane) {
      sreg = s;
#pragma unroll
      for (int h = 0; h < H; ++h) vreg[h] = vv[h];
    }
  }
  // cross-lane (m, den) merge
#pragma unroll
  for (int off = 32; off; off >>= 1) {
#pragma unroll
    for (int h = 0; h < H; ++h) {
      float om = __shfl_xor(m[h], off);
      float od = __shfl_xor(den[h], off);
      float nm = fmaxf(m[h], om);
      den[h] = den[h] * __expf(m[h] - nm) + od * __expf(om - nm);
      m[h] = nm;
    }
  }
  float rden[H];
#pragma unroll
  for (int h = 0; h < H; ++h) rden[h] = 1.f / den[h];
  // ---- phase B: alpha per edge once; shfl-broadcast; gather-FMA unroll x2 ----
  float acc0 = 0.f, acc1 = 0.f, acc2 = 0.f, acc3 = 0.f;
  for (int c0 = 0; c0 < deg; c0 += 64) {
    const int ce = min(64, deg - c0);
    float ar[H];
    int sr = 0;
#pragma unroll
    for (int h = 0; h < H; ++h) ar[h] = 0.f;
    if (c0 == 0) {
      sr = sreg;
#pragma unroll
      for (int h = 0; h < H; ++h) ar[h] = __expf(vreg[h] - m[h]) * rden[h];
    } else {
      int i = c0 + lane;
      if (i < deg) {
        int s = srcs[b0 + i];
        sr = s;
        float vv[H];
        if constexpr (H == 4) {
          float4 ev = *(const float4*)&es[(size_t)s * 4];
          vv[0] = ev.x + edv[0];
          vv[1] = ev.y + edv[1];
          vv[2] = ev.z + edv[2];
          vv[3] = ev.w + edv[3];
        } else {
          vv[0] = es[s] + edv[0];
        }
#pragma unroll
        for (int h = 0; h < H; ++h) {
          float v = vv[h];
          v = v > 0.f ? v : 0.2f * v;
          ar[h] = __expf(v - m[h]) * rden[h];
        }
      }
    }
    int e = 0;
    for (; e + 2 <= ce; e += 2) {
      int sA = __shfl(sr, e);
      int sB = __shfl(sr, e + 1);
      const unsigned short* wpA = Whb + (size_t)sA * (H * D);
      const unsigned short* wpB = Whb + (size_t)sB * (H * D);
      float aA[H], aB[H];
#pragma unroll
      for (int h = 0; h < H; ++h) {
        aA[h] = __shfl(ar[h], e);
        aB[h] = __shfl(ar[h], e + 1);
      }
#pragma unroll
      for (int h = 0; h < H; ++h) {
        unsigned vA = *(const unsigned*)&wpA[h * D + 2 * lane];
        unsigned vB = *(const unsigned*)&wpB[h * D + 2 * lane];
        acc0 += aA[h] * bf2f((unsigned short)(vA & 0xffffu));
        acc1 += aA[h] * bf2f((unsigned short)(vA >> 16));
        acc2 += aB[h] * bf2f((unsigned short)(vB & 0xffffu));
        acc3 += aB[h] * bf2f((unsigned short)(vB >> 16));
      }
    }
    if (e < ce) {
      int sA = __shfl(sr, e);
      const unsigned short* wpA = Whb + (size_t)sA * (H * D);
      float aA[H];
#pragma unroll
      for (int h = 0; h < H; ++h) aA[h] = __shfl(ar[h], e);
#pragma unroll
      for (int h = 0; h < H; ++h) {
        unsigned vA = *(const unsigned*)&wpA[h * D + 2 * lane];
        acc0 += aA[h] * bf2f((unsigned short)(vA & 0xffffu));
        acc1 += aA[h] * bf2f((unsigned short)(vA >> 16));
      }
    }
  }
  float o0 = (acc0 + acc2) * (1.0f / H);
  float o1 = (acc1 + acc3) * (1.0f / H);
  if constexpr (EPI == 1) {
    o0 = o0 > 0.f ? o0 : expm1f(o0);
    o1 = o1 > 0.f ? o1 : expm1f(o1);
    ((unsigned*)(outb + (size_t)t * D))[lane] =
        (unsigned)f2b(o0) | ((unsigned)f2b(o1) << 16);
  }
  ((float2*)(outf + (size_t)t * D))[lane] = make_float2(o0, o1);
}

// ---------- fused GRU (32-row tiles): x=elu(agg); gi=x@Wih^T; gh=h@Whh^T; gates ----------
__global__ void __launch_bounds__(256) k_gru_mfma(const float* __restrict__ agg,
                                                  const float* __restrict__ hf,
                                                  const unsigned short* __restrict__ hb,
                                                  const unsigned short* __restrict__ Bih,
                                                  const unsigned short* __restrict__ Bhh,
                                                  const float* __restrict__ bih,
                                                  const float* __restrict__ bhh,
                                                  float* __restrict__ houtf,
                                                  unsigned short* __restrict__ houtb) {
  const int n0 = blockIdx.x * 32;
  const int w = threadIdx.x >> 6;
  const int lane = threadIdx.x & 63;
  const int r = lane & 15, g = lane >> 4;
  f32x4 ai[3][2][2], ah[3][2][2];  // [gate][t][rowtile]
#pragma unroll
  for (int p = 0; p < 3; ++p)
#pragma unroll
    for (int t = 0; t < 2; ++t)
#pragma unroll
      for (int m = 0; m < 2; ++m) {
        ai[p][t][m] = (f32x4)0.f;
        ah[p][t][m] = (f32x4)0.f;
      }
  const int koff = g << 3;
#pragma unroll
  for (int kb = 0; kb < 4; ++kb) {
    bf16x8 ax[2], ahr[2];
#pragma unroll
    for (int m = 0; m < 2; ++m) {
      const size_t abase = (size_t)(n0 + m * 16 + r) * 128 + kb * 32 + koff;
      float4 a0 = *(const float4*)&agg[abase];
      float4 a1 = *(const float4*)&agg[abase + 4];
      float v0 = a0.x > 0.f ? a0.x : expm1f(a0.x);
      float v1 = a0.y > 0.f ? a0.y : expm1f(a0.y);
      float v2 = a0.z > 0.f ? a0.z : expm1f(a0.z);
      float v3 = a0.w > 0.f ? a0.w : expm1f(a0.w);
      float v4 = a1.x > 0.f ? a1.x : expm1f(a1.x);
      float v5 = a1.y > 0.f ? a1.y : expm1f(a1.y);
      float v6 = a1.z > 0.f ? a1.z : expm1f(a1.z);
      float v7 = a1.w > 0.f ? a1.w : expm1f(a1.w);
      bf16x8 axv;
      axv[0] = (short)f2b(v0); axv[1] = (short)f2b(v1);
      axv[2] = (short)f2b(v2); axv[3] = (short)f2b(v3);
      axv[4] = (short)f2b(v4); axv[5] = (short)f2b(v5);
      axv[6] = (short)f2b(v6); axv[7] = (short)f2b(v7);
      ax[m] = axv;
      ahr[m] = *(const bf16x8*)&hb[abase];
    }
#pragma unroll
    for (int p = 0; p < 3; ++p) {
#pragma unroll
      for (int t = 0; t < 2; ++t) {
        const int ct = p * 8 + w * 2 + t;
        bf16x8 bi = *(const bf16x8*)&Bih[((size_t)(kb * 24 + ct) * 64 + lane) * 8];
        bf16x8 bh = *(const bf16x8*)&Bhh[((size_t)(kb * 24 + ct) * 64 + lane) * 8];
#pragma unroll
        for (int m = 0; m < 2; ++m) {
          ai[p][t][m] = __builtin_amdgcn_mfma_f32_16x16x32_bf16(ax[m], bi, ai[p][t][m], 0, 0, 0);
          ah[p][t][m] = __builtin_amdgcn_mfma_f32_16x16x32_bf16(ahr[m], bh, ah[p][t][m], 0, 0, 0);
        }
      }
    }
  }
#pragma unroll
  for (int m = 0; m < 2; ++m) {
#pragma unroll
    for (int t = 0; t < 2; ++t) {
      const int j = (w * 2 + t) * 16 + r;
      const float bir = bih[j], biz = bih[128 + j], bin = bih[256 + j];
      const float bhr = bhh[j], bhz = bhh[128 + j], bhn = bhh[256 + j];
#pragma unroll
      for (int i = 0; i < 4; ++i) {
        const int row = n0 + m * 16 + g * 4 + i;
        float rr = sigmoidf_(ai[0][t][m][i] + bir + ah[0][t][m][i] + bhr);
        float z = sigmoidf_(ai[1][t][m][i] + biz + ah[1][t][m][i] + bhz);
        float nn = tanhf(ai[2][t][m][i] + bin + rr * (ah[2][t][m][i] + bhn));
        float hp = hf[(size_t)row * 128 + j];
        float o = (1.f - z) * nn + z * hp;
        houtf[(size_t)row * 128 + j] = o;
        houtb[(size_t)row * 128 + j] = f2b(o);
      }
    }
  }
}

// ---------- final: out[n] = sigmoid(dot(h[n,:], W5) + b5) ----------
__global__ void __launch_bounds__(256) k_final(const float* __restrict__ h, const float* __restrict__ W5,
                                               const float* __restrict__ b5, float* __restrict__ out, int N) {
  int w = blockIdx.x * 4 + (threadIdx.x >> 6);
  int lane = threadIdx.x & 63;
  if (w >= N) return;
  float x = h[(size_t)w * D + lane] * W5[lane] + h[(size_t)w * D + lane + 64] * W5[lane + 64];
#pragma unroll
  for (int off = 32; off; off >>= 1) x += __shfl_down(x, off);
  if (lane == 0) out[w] = sigmoidf_(x + b5[0]);
}

extern "C" void kernel_launch(void* const* d_in, const int* in_sizes, int n_in,
                              void* d_out, int out_size, void* d_ws, size_t ws_size,
                              hipStream_t stream) {
  const float* h0 = (const float*)d_in[0];
  const int* ei = (const int*)d_in[1];
  const float* W1 = (const float*)d_in[2];
  const float* as1 = (const float*)d_in[3];
  const float* ad1 = (const float*)d_in[4];
  const float* W2 = (const float*)d_in[5];
  const float* as2 = (const float*)d_in[6];
  const float* ad2 = (const float*)d_in[7];
  const float* W3 = (const float*)d_in[8];
  const float* as3 = (const float*)d_in[9];
  const float* ad3 = (const float*)d_in[10];
  const float* W4 = (const float*)d_in[11];
  const float* as4 = (const float*)d_in[12];
  const float* ad4 = (const float*)d_in[13];
  const float* Wih = (const float*)d_in[14];
  const float* Whh = (const float*)d_in[15];
  const float* bih = (const float*)d_in[16];
  const float* bhh = (const float*)d_in[17];
  const float* W5 = (const float*)d_in[18];
  const float* b5 = (const float*)d_in[19];

  const int N = in_sizes[0] / D;  // 20000
  const int E = in_sizes[1] / 2;  // 320000
  const int* src = ei;
  const int* dst = ei + E;

  // ---- workspace layout ----
  float* ws = (float*)d_ws;
  unsigned short* Whb = (unsigned short*)ws;          // N*512 us
  float* agg = ws + (size_t)N * 256;                  // N*128
  float* hA = agg + (size_t)N * 128;                  // N*128
  float* hB = hA + (size_t)N * 128;                   // N*128
  float* es = hB + (size_t)N * 128;                   // N*4
  float* ed = es + (size_t)N * 4;                     // N*4
  unsigned short* h0b = (unsigned short*)(ed + (size_t)N * 4);  // N*128 us
  unsigned short* hAb = h0b + (size_t)N * 128;        // N*128 us
  unsigned short* hBb = hAb + (size_t)N * 128;        // N*128 us
  unsigned short* BpW = hBb + (size_t)N * 128;        // 128*512 us
  unsigned short* Bih = BpW + 128 * 512;              // 128*384 us
  unsigned short* Bhh = Bih + 128 * 384;              // 128*384 us
  int* deg = (int*)(Bhh + 128 * 384);                 // N
  int* rowptr = deg + N;                              // N+1
  int* fill = rowptr + N + 1;                         // N
  int* srcs = fill + N;                               // E

  // ---- one-time prep ----
  k_f2b<<<(N * 128 + 255) / 256, 256, 0, stream>>>(h0, h0b, N * 128);
  k_pack_gru<<<(128 * 384 + 255) / 256, 256, 0, stream>>>(Wih, Bih);
  k_pack_gru<<<(128 * 384 + 255) / 256, 256, 0, stream>>>(Whh, Bhh);
  hipMemsetAsync(deg, 0, (size_t)N * 4, stream);
  k_hist<<<(E + 255) / 256, 256, 0, stream>>>(dst, deg, E);
  k_scan<<<1, 1024, 0, stream>>>(deg, rowptr, fill, N);
  k_scatter<<<(E + 255) / 256, 256, 0, stream>>>(src, dst, fill, srcs, E);

  const int gW = N / 32;       // 625
  const int gE = (N + 3) / 4;  // 5000
  // ---- layer 1: H=4, no GRU ----
  k_pack_w<512><<<(128 * 512 + 255) / 256, 256, 0, stream>>>(W1, BpW);
  k_wh_mfma<512, true><<<gW, 256, 0, stream>>>(h0b, BpW, Whb, as1, ad1, es, ed);
  k_edge_fused<4, 1><<<gE, 256, 0, stream>>>(rowptr, srcs, es, ed, Whb, hA, hAb, N);
  // ---- layer 2: H=4, GRU ----
  k_pack_w<512><<<(128 * 512 + 255) / 256, 256, 0, stream>>>(W2, BpW);
  k_wh_mfma<512, true><<<gW, 256, 0, stream>>>(hAb, BpW, Whb, as2, ad2, es, ed);
  k_edge_fused<4, 0><<<gE, 256, 0, stream>>>(rowptr, srcs, es, ed, Whb, agg, nullptr, N);
  k_gru_mfma<<<gW, 256, 0, stream>>>(agg, hA, hAb, Bih, Bhh, bih, bhh, hB, hBb);
  // ---- layer 3: H=4, GRU ----
  k_pack_w<512><<<(128 * 512 + 255) / 256, 256, 0, stream>>>(W3, BpW);
  k_wh_mfma<512, true><<<gW, 256, 0, stream>>>(hBb, BpW, Whb, as3, ad3, es, ed);
  k_edge_fused<4, 0><<<gE, 256, 0, stream>>>(rowptr, srcs, es, ed, Whb, agg, nullptr, N);
  k_gru_mfma<<<gW, 256, 0, stream>>>(agg, hB, hBb, Bih, Bhh, bih, bhh, hA, hAb);
  // ---- layer 4: H=1, GRU ----
  k_pack_w<128><<<(128 * 128 + 255) / 256, 256, 0, stream>>>(W4, BpW);
  k_wh_mfma<128, false><<<gW, 256, 0, stream>>>(hAb, BpW, Whb, nullptr, nullptr, nullptr, nullptr);
  k_es_ed1<<<(N + 3) / 4, 256, 0, stream>>>(Whb, as4, ad4, es, ed, N);
  k_edge_fused<1, 0><<<gE, 256, 0, stream>>>(rowptr, srcs, es, ed, Whb, agg, nullptr, N);
  k_gru_mfma<<<gW, 256, 0, stream>>>(agg, hA, hAb, Bih, Bhh, bih, bhh, hB, hBb);

  // ---- output head ----
  k_final<<<(N + 3) / 4, 256, 0, stream>>>(hB, W5, b5, (float*)d_out, N);
}

// Round 5
// 397.108 us; speedup vs baseline: 4.1212x; 1.0494x over previous
//
#include <hip/hip_runtime.h>
#include <math.h>

#define D 128

typedef __attribute__((ext_vector_type(8))) short bf16x8;
typedef __attribute__((ext_vector_type(4))) float f32x4;

__device__ __forceinline__ float sigmoidf_(float x) { return 1.f / (1.f + __expf(-x)); }
__device__ __forceinline__ float bf2f(unsigned short u) { return __uint_as_float(((unsigned)u) << 16); }
__device__ __forceinline__ unsigned short f2b(float f) {
  unsigned u = __float_as_uint(f);
  return (unsigned short)((u + 0x7fffu + ((u >> 16) & 1u)) >> 16);  // RNE
}

// ---------- fp32 -> bf16 convert ----------
__global__ void __launch_bounds__(256) k_f2b(const float* __restrict__ in,
                                             unsigned short* __restrict__ out, int n) {
  int i = blockIdx.x * 256 + threadIdx.x;
  if (i < n) out[i] = f2b(in[i]);
}

// ---------- pack W[h,k,d] -> MFMA B-fragment layout ----------
template <int NCOLS>
__global__ void __launch_bounds__(256) k_pack_w(const float* __restrict__ W,
                                                unsigned short* __restrict__ Bp) {
  int i = blockIdx.x * 256 + threadIdx.x;
  if (i >= 128 * NCOLS) return;
  int j = i & 7;
  int lane = (i >> 3) & 63;
  int rest = i >> 9;  // kb*(NCOLS/16)+db
  int db = rest % (NCOLS / 16);
  int kb = rest / (NCOLS / 16);
  int k = kb * 32 + ((lane >> 4) << 3) + j;
  int col = db * 16 + (lane & 15);
  int h = col >> 7, d = col & 127;
  Bp[i] = f2b(W[((size_t)h * 128 + k) * 128 + d]);
}

// ---------- pack GRU weight S[384][128] as B[k][col]=S[col][k] ----------
__global__ void __launch_bounds__(256) k_pack_gru(const float* __restrict__ S,
                                                  unsigned short* __restrict__ Bp) {
  int i = blockIdx.x * 256 + threadIdx.x;
  if (i >= 128 * 384) return;
  int j = i & 7;
  int lane = (i >> 3) & 63;
  int rest = i >> 9;  // kb*24+db
  int db = rest % 24;
  int kb = rest / 24;
  int k = kb * 32 + ((lane >> 4) << 3) + j;
  int col = db * 16 + (lane & 15);
  Bp[i] = f2b(S[(size_t)col * 128 + k]);
}

// ---------- MFMA GEMM: 32-row tiles; optional fused es/ed epilogue (NCOLS=512) ----------
template <int NCOLS, bool FUSE>
__global__ void __launch_bounds__(256) k_wh_mfma(const unsigned short* __restrict__ hb,
                                                 const unsigned short* __restrict__ Bp,
                                                 unsigned short* __restrict__ Whb,
                                                 const float* __restrict__ a_src,
                                                 const float* __restrict__ a_dst,
                                                 float* __restrict__ es,
                                                 float* __restrict__ ed) {
  const int n0 = blockIdx.x * 32;
  const int w = threadIdx.x >> 6;
  const int lane = threadIdx.x & 63;
  const int r = lane & 15, g = lane >> 4;
  constexpr int TPW = NCOLS / 64;
  f32x4 acc[2][TPW];
#pragma unroll
  for (int m = 0; m < 2; ++m)
#pragma unroll
    for (int t = 0; t < TPW; ++t) acc[m][t] = (f32x4)0.f;
  const int koff = g << 3;
#pragma unroll
  for (int kb = 0; kb < 4; ++kb) {
    bf16x8 a0 = *(const bf16x8*)&hb[(size_t)(n0 + r) * 128 + kb * 32 + koff];
    bf16x8 a1 = *(const bf16x8*)&hb[(size_t)(n0 + 16 + r) * 128 + kb * 32 + koff];
#pragma unroll
    for (int t = 0; t < TPW; ++t) {
      const int ct = w * TPW + t;
      bf16x8 b = *(const bf16x8*)&Bp[((size_t)(kb * (NCOLS / 16) + ct) * 64 + lane) * 8];
      acc[0][t] = __builtin_amdgcn_mfma_f32_16x16x32_bf16(a0, b, acc[0][t], 0, 0, 0);
      acc[1][t] = __builtin_amdgcn_mfma_f32_16x16x32_bf16(a1, b, acc[1][t], 0, 0, 0);
    }
  }
#pragma unroll
  for (int m = 0; m < 2; ++m) {
    const int rbase = n0 + m * 16 + g * 4;
#pragma unroll
    for (int t = 0; t < TPW; ++t) {
      const int col = (w * TPW + t) * 16 + r;
#pragma unroll
      for (int i = 0; i < 4; ++i) {
        Whb[(size_t)(rbase + i) * NCOLS + col] = f2b(acc[m][t][i]);
      }
    }
  }
  if constexpr (FUSE) {
    // head = w; d = t*16 + r
    float av[TPW], bv[TPW];
#pragma unroll
    for (int t = 0; t < TPW; ++t) {
      av[t] = a_src[w * 128 + t * 16 + r];
      bv[t] = a_dst[w * 128 + t * 16 + r];
    }
#pragma unroll
    for (int m = 0; m < 2; ++m) {
      float sp[4] = {}, dp[4] = {};
#pragma unroll
      for (int t = 0; t < TPW; ++t)
#pragma unroll
        for (int i = 0; i < 4; ++i) {
          sp[i] += acc[m][t][i] * av[t];
          dp[i] += acc[m][t][i] * bv[t];
        }
#pragma unroll
      for (int off = 1; off < 16; off <<= 1)
#pragma unroll
        for (int i = 0; i < 4; ++i) {
          sp[i] += __shfl_xor(sp[i], off);
          dp[i] += __shfl_xor(dp[i], off);
        }
      if (r == 0) {
        const int rbase = n0 + m * 16 + g * 4;
#pragma unroll
        for (int i = 0; i < 4; ++i) {
          es[(size_t)(rbase + i) * 4 + w] = sp[i];
          ed[(size_t)(rbase + i) * 4 + w] = dp[i];
        }
      }
    }
  }
}

// ---------- es/ed for H=1 (layer 4) ----------
__global__ void __launch_bounds__(256) k_es_ed1(const unsigned short* __restrict__ Whb,
                                                const float* __restrict__ a_src,
                                                const float* __restrict__ a_dst,
                                                float* __restrict__ es,
                                                float* __restrict__ ed, int N) {
  int w = blockIdx.x * 4 + (threadIdx.x >> 6);
  int lane = threadIdx.x & 63;
  if (w >= N) return;
  const unsigned short* row = Whb + (size_t)w * D;
  float x0 = bf2f(row[lane]), x1 = bf2f(row[lane + 64]);
  float s = x0 * a_src[lane] + x1 * a_src[lane + 64];
  float t = x0 * a_dst[lane] + x1 * a_dst[lane + 64];
#pragma unroll
  for (int off = 32; off; off >>= 1) {
    s += __shfl_down(s, off);
    t += __shfl_down(t, off);
  }
  if (lane == 0) {
    es[w] = s;
    ed[w] = t;
  }
}

// ---------- CSR build ----------
__global__ void __launch_bounds__(256) k_hist(const int* __restrict__ dst, int* __restrict__ deg, int E) {
  int e = blockIdx.x * 256 + threadIdx.x;
  if (e < E) atomicAdd(&deg[dst[e]], 1);
}

__global__ void __launch_bounds__(1024) k_scan(const int* __restrict__ deg, int* __restrict__ rowptr,
                                               int* __restrict__ fill, int N) {
  __shared__ int part[1024];
  const int tid = threadIdx.x;
  const int chunk = (N + 1023) / 1024;
  const int b = tid * chunk;
  const int e = min(N, b + chunk);
  int s = 0;
  for (int i = b; i < e; ++i) s += deg[i];
  part[tid] = s;
  __syncthreads();
  for (int off = 1; off < 1024; off <<= 1) {
    int v = (tid >= off) ? part[tid - off] : 0;
    __syncthreads();
    part[tid] += v;
    __syncthreads();
  }
  int run = (tid == 0) ? 0 : part[tid - 1];
  for (int i = b; i < e; ++i) {
    rowptr[i] = run;
    fill[i] = run;
    run += deg[i];
  }
  if (b < N && e == N) rowptr[N] = run;
}

__global__ void __launch_bounds__(256) k_scatter(const int* __restrict__ src, const int* __restrict__ dst,
                                                 int* __restrict__ fill, int* __restrict__ srcs, int E) {
  int e = blockIdx.x * 256 + threadIdx.x;
  if (e >= E) return;
  int pos = atomicAdd(&fill[dst[e]], 1);
  srcs[pos] = src[e];
}

// ---------- fused edge phase v3: 16-lane group per node ----------
// lane q of a group owns d-slice [8q, 8q+8); 16 nodes/block.
// EPI=0: write agg f32; EPI=1: write elu(agg) f32 + bf16; EPI=2: write elu(agg) bf16 only
template <int H, int EPI>
__global__ void __launch_bounds__(256) k_edge_fused(const int* __restrict__ rowptr,
                                                    const int* __restrict__ srcs,
                                                    const float* __restrict__ es,
                                                    const float* __restrict__ ed,
                                                    const unsigned short* __restrict__ Whb,
                                                    float* __restrict__ outf,
                                                    unsigned short* __restrict__ outb,
                                                    int N) {
  const int t = blockIdx.x * 16 + (threadIdx.x >> 4);
  if (t >= N) return;
  const int lane = threadIdx.x & 63;
  const int q = lane & 15;
  const int gbase = lane & 48;  // group's lane 0 within wave
  const int b0 = rowptr[t];
  const int deg = rowptr[t + 1] - b0;
  if (deg == 0) {
    if constexpr (EPI != 2) {
      *(float4*)&outf[(size_t)t * D + q * 8] = make_float4(0.f, 0.f, 0.f, 0.f);
      *(float4*)&outf[(size_t)t * D + q * 8 + 4] = make_float4(0.f, 0.f, 0.f, 0.f);
    }
    if constexpr (EPI != 0) {
      *(uint4*)&outb[(size_t)t * D + q * 8] = make_uint4(0u, 0u, 0u, 0u);
    }
    return;
  }
  float edv[H];
#pragma unroll
  for (int h = 0; h < H; ++h) edv[h] = ed[t * H + h];
  // ---- phase A: online softmax over this node's edges (16 lanes) ----
  float m[H], den[H], vreg[H];
  int sreg = 0;
#pragma unroll
  for (int h = 0; h < H; ++h) {
    m[h] = -1e30f;
    den[h] = 0.f;
    vreg[h] = -1e30f;
  }
  for (int i = q; i < deg; i += 16) {
    int s = srcs[b0 + i];
    float vv[H];
    if constexpr (H == 4) {
      float4 ev = *(const float4*)&es[(size_t)s * 4];
      vv[0] = ev.x + edv[0];
      vv[1] = ev.y + edv[1];
      vv[2] = ev.z + edv[2];
      vv[3] = ev.w + edv[3];
    } else {
      vv[0] = es[s] + edv[0];
    }
#pragma unroll
    for (int h = 0; h < H; ++h) {
      float v = vv[h];
      v = v > 0.f ? v : 0.2f * v;
      vv[h] = v;
      float nm = fmaxf(m[h], v);
      den[h] = den[h] * __expf(m[h] - nm) + __expf(v - nm);
      m[h] = nm;
    }
    if (i == q) {
      sreg = s;
#pragma unroll
      for (int h = 0; h < H; ++h) vreg[h] = vv[h];
    }
  }
  // group-wide (16-lane) merge
#pragma unroll
  for (int off = 1; off < 16; off <<= 1) {
#pragma unroll
    for (int h = 0; h < H; ++h) {
      float om = __shfl_xor(m[h], off);
      float od = __shfl_xor(den[h], off);
      float nm = fmaxf(m[h], om);
      den[h] = den[h] * __expf(m[h] - nm) + od * __expf(om - nm);
      m[h] = nm;
    }
  }
  float rden[H];
#pragma unroll
  for (int h = 0; h < H; ++h) rden[h] = 1.f / den[h];
  // ---- phase B: gather-FMA; lane q covers d = [8q, 8q+8) ----
  float acc[8];
#pragma unroll
  for (int j = 0; j < 8; ++j) acc[j] = 0.f;
  const unsigned short* whq = Whb + q * 8;
  for (int c0 = 0; c0 < deg; c0 += 16) {
    const int ce = min(16, deg - c0);
    float ar[H];
    int sr = 0;
#pragma unroll
    for (int h = 0; h < H; ++h) ar[h] = 0.f;
    if (c0 == 0) {
      sr = sreg;
#pragma unroll
      for (int h = 0; h < H; ++h) ar[h] = __expf(vreg[h] - m[h]) * rden[h];
    } else {
      int i = c0 + q;
      if (i < deg) {
        int s = srcs[b0 + i];
        sr = s;
        float vv[H];
        if constexpr (H == 4) {
          float4 ev = *(const float4*)&es[(size_t)s * 4];
          vv[0] = ev.x + edv[0];
          vv[1] = ev.y + edv[1];
          vv[2] = ev.z + edv[2];
          vv[3] = ev.w + edv[3];
        } else {
          vv[0] = es[s] + edv[0];
        }
#pragma unroll
        for (int h = 0; h < H; ++h) {
          float v = vv[h];
          v = v > 0.f ? v : 0.2f * v;
          ar[h] = __expf(v - m[h]) * rden[h];
        }
      }
    }
#pragma unroll 2
    for (int e = 0; e < ce; ++e) {
      int s = __shfl(sr, gbase + e);
      float a[H];
#pragma unroll
      for (int h = 0; h < H; ++h) a[h] = __shfl(ar[h], gbase + e);
      const unsigned short* wp = whq + (size_t)s * (H * D);
#pragma unroll
      for (int h = 0; h < H; ++h) {
        bf16x8 v = *(const bf16x8*)&wp[h * D];
#pragma unroll
        for (int j = 0; j < 8; ++j) {
          acc[j] += a[h] * bf2f((unsigned short)v[j]);
        }
      }
    }
  }
  float o[8];
#pragma unroll
  for (int j = 0; j < 8; ++j) o[j] = acc[j] * (1.0f / H);
  if constexpr (EPI != 0) {
#pragma unroll
    for (int j = 0; j < 8; ++j) o[j] = o[j] > 0.f ? o[j] : expm1f(o[j]);
    uint4 pk;
    pk.x = (unsigned)f2b(o[0]) | ((unsigned)f2b(o[1]) << 16);
    pk.y = (unsigned)f2b(o[2]) | ((unsigned)f2b(o[3]) << 16);
    pk.z = (unsigned)f2b(o[4]) | ((unsigned)f2b(o[5]) << 16);
    pk.w = (unsigned)f2b(o[6]) | ((unsigned)f2b(o[7]) << 16);
    *(uint4*)&outb[(size_t)t * D + q * 8] = pk;
  }
  if constexpr (EPI != 2) {
    *(float4*)&outf[(size_t)t * D + q * 8] = make_float4(o[0], o[1], o[2], o[3]);
    *(float4*)&outf[(size_t)t * D + q * 8 + 4] = make_float4(o[4], o[5], o[6], o[7]);
  }
}

// ---------- fused GRU (32-row tiles): gi=xb@Wih^T; gh=hb@Whh^T; gates ----------
// xb = bf16(elu(agg)) precomputed by the edge kernel.
__global__ void __launch_bounds__(256) k_gru_mfma(const unsigned short* __restrict__ xb,
                                                  const unsigned short* __restrict__ hb,
                                                  const float* __restrict__ hf,
                                                  const unsigned short* __restrict__ Bih,
                                                  const unsigned short* __restrict__ Bhh,
                                                  const float* __restrict__ bih,
                                                  const float* __restrict__ bhh,
                                                  float* __restrict__ houtf,
                                                  unsigned short* __restrict__ houtb) {
  const int n0 = blockIdx.x * 32;
  const int w = threadIdx.x >> 6;
  const int lane = threadIdx.x & 63;
  const int r = lane & 15, g = lane >> 4;
  f32x4 ai[3][2][2], ah[3][2][2];  // [gate][t][rowtile]
#pragma unroll
  for (int p = 0; p < 3; ++p)
#pragma unroll
    for (int t = 0; t < 2; ++t)
#pragma unroll
      for (int m = 0; m < 2; ++m) {
        ai[p][t][m] = (f32x4)0.f;
        ah[p][t][m] = (f32x4)0.f;
      }
  const int koff = g << 3;
#pragma unroll
  for (int kb = 0; kb < 4; ++kb) {
    bf16x8 ax[2], ahr[2];
#pragma unroll
    for (int m = 0; m < 2; ++m) {
      const size_t abase = (size_t)(n0 + m * 16 + r) * 128 + kb * 32 + koff;
      ax[m] = *(const bf16x8*)&xb[abase];
      ahr[m] = *(const bf16x8*)&hb[abase];
    }
#pragma unroll
    for (int p = 0; p < 3; ++p) {
#pragma unroll
      for (int t = 0; t < 2; ++t) {
        const int ct = p * 8 + w * 2 + t;
        bf16x8 bi = *(const bf16x8*)&Bih[((size_t)(kb * 24 + ct) * 64 + lane) * 8];
        bf16x8 bh = *(const bf16x8*)&Bhh[((size_t)(kb * 24 + ct) * 64 + lane) * 8];
#pragma unroll
        for (int m = 0; m < 2; ++m) {
          ai[p][t][m] = __builtin_amdgcn_mfma_f32_16x16x32_bf16(ax[m], bi, ai[p][t][m], 0, 0, 0);
          ah[p][t][m] = __builtin_amdgcn_mfma_f32_16x16x32_bf16(ahr[m], bh, ah[p][t][m], 0, 0, 0);
        }
      }
    }
  }
#pragma unroll
  for (int m = 0; m < 2; ++m) {
#pragma unroll
    for (int t = 0; t < 2; ++t) {
      const int j = (w * 2 + t) * 16 + r;
      const float bir = bih[j], biz = bih[128 + j], bin = bih[256 + j];
      const float bhr = bhh[j], bhz = bhh[128 + j], bhn = bhh[256 + j];
#pragma unroll
      for (int i = 0; i < 4; ++i) {
        const int row = n0 + m * 16 + g * 4 + i;
        float rr = sigmoidf_(ai[0][t][m][i] + bir + ah[0][t][m][i] + bhr);
        float z = sigmoidf_(ai[1][t][m][i] + biz + ah[1][t][m][i] + bhz);
        float nn = tanhf(ai[2][t][m][i] + bin + rr * (ah[2][t][m][i] + bhn));
        float hp = hf[(size_t)row * 128 + j];
        float o = (1.f - z) * nn + z * hp;
        houtf[(size_t)row * 128 + j] = o;
        houtb[(size_t)row * 128 + j] = f2b(o);
      }
    }
  }
}

// ---------- final: out[n] = sigmoid(dot(h[n,:], W5) + b5) ----------
__global__ void __launch_bounds__(256) k_final(const float* __restrict__ h, const float* __restrict__ W5,
                                               const float* __restrict__ b5, float* __restrict__ out, int N) {
  int w = blockIdx.x * 4 + (threadIdx.x >> 6);
  int lane = threadIdx.x & 63;
  if (w >= N) return;
  float x = h[(size_t)w * D + lane] * W5[lane] + h[(size_t)w * D + lane + 64] * W5[lane + 64];
#pragma unroll
  for (int off = 32; off; off >>= 1) x += __shfl_down(x, off);
  if (lane == 0) out[w] = sigmoidf_(x + b5[0]);
}

extern "C" void kernel_launch(void* const* d_in, const int* in_sizes, int n_in,
                              void* d_out, int out_size, void* d_ws, size_t ws_size,
                              hipStream_t stream) {
  const float* h0 = (const float*)d_in[0];
  const int* ei = (const int*)d_in[1];
  const float* W1 = (const float*)d_in[2];
  const float* as1 = (const float*)d_in[3];
  const float* ad1 = (const float*)d_in[4];
  const float* W2 = (const float*)d_in[5];
  const float* as2 = (const float*)d_in[6];
  const float* ad2 = (const float*)d_in[7];
  const float* W3 = (const float*)d_in[8];
  const float* as3 = (const float*)d_in[9];
  const float* ad3 = (const float*)d_in[10];
  const float* W4 = (const float*)d_in[11];
  const float* as4 = (const float*)d_in[12];
  const float* ad4 = (const float*)d_in[13];
  const float* Wih = (const float*)d_in[14];
  const float* Whh = (const float*)d_in[15];
  const float* bih = (const float*)d_in[16];
  const float* bhh = (const float*)d_in[17];
  const float* W5 = (const float*)d_in[18];
  const float* b5 = (const float*)d_in[19];

  const int N = in_sizes[0] / D;  // 20000
  const int E = in_sizes[1] / 2;  // 320000
  const int* src = ei;
  const int* dst = ei + E;

  // ---- workspace layout ----
  float* ws = (float*)d_ws;
  unsigned short* Whb = (unsigned short*)ws;          // N*512 us
  float* hA = ws + (size_t)N * 256;                   // N*128 f32
  float* hB = hA + (size_t)N * 128;                   // N*128 f32
  unsigned short* xb = (unsigned short*)(hB + (size_t)N * 128);  // N*128 us
  float* es = (float*)(xb + (size_t)N * 128);         // N*4
  float* ed = es + (size_t)N * 4;                     // N*4
  unsigned short* h0b = (unsigned short*)(ed + (size_t)N * 4);   // N*128 us
  unsigned short* hAb = h0b + (size_t)N * 128;        // N*128 us
  unsigned short* hBb = hAb + (size_t)N * 128;        // N*128 us
  unsigned short* BpW = hBb + (size_t)N * 128;        // 128*512 us
  unsigned short* Bih = BpW + 128 * 512;              // 128*384 us
  unsigned short* Bhh = Bih + 128 * 384;              // 128*384 us
  int* deg = (int*)(Bhh + 128 * 384);                 // N
  int* rowptr = deg + N;                              // N+1
  int* fill = rowptr + N + 1;                         // N
  int* srcs = fill + N;                               // E

  // ---- one-time prep ----
  k_f2b<<<(N * 128 + 255) / 256, 256, 0, stream>>>(h0, h0b, N * 128);
  k_pack_gru<<<(128 * 384 + 255) / 256, 256, 0, stream>>>(Wih, Bih);
  k_pack_gru<<<(128 * 384 + 255) / 256, 256, 0, stream>>>(Whh, Bhh);
  hipMemsetAsync(deg, 0, (size_t)N * 4, stream);
  k_hist<<<(E + 255) / 256, 256, 0, stream>>>(dst, deg, E);
  k_scan<<<1, 1024, 0, stream>>>(deg, rowptr, fill, N);
  k_scatter<<<(E + 255) / 256, 256, 0, stream>>>(src, dst, fill, srcs, E);

  const int gW = N / 32;        // 625
  const int gE = (N + 15) / 16; // 1250
  // ---- layer 1: H=4, no GRU; edge emits elu as f32 (hA) + bf16 (hAb) ----
  k_pack_w<512><<<(128 * 512 + 255) / 256, 256, 0, stream>>>(W1, BpW);
  k_wh_mfma<512, true><<<gW, 256, 0, stream>>>(h0b, BpW, Whb, as1, ad1, es, ed);
  k_edge_fused<4, 1><<<gE, 256, 0, stream>>>(rowptr, srcs, es, ed, Whb, hA, hAb, N);
  // ---- layer 2: H=4, GRU; edge emits xb bf16 only ----
  k_pack_w<512><<<(128 * 512 + 255) / 256, 256, 0, stream>>>(W2, BpW);
  k_wh_mfma<512, true><<<gW, 256, 0, stream>>>(hAb, BpW, Whb, as2, ad2, es, ed);
  k_edge_fused<4, 2><<<gE, 256, 0, stream>>>(rowptr, srcs, es, ed, Whb, nullptr, xb, N);
  k_gru_mfma<<<gW, 256, 0, stream>>>(xb, hAb, hA, Bih, Bhh, bih, bhh, hB, hBb);
  // ---- layer 3: H=4, GRU ----
  k_pack_w<512><<<(128 * 512 + 255) / 256, 256, 0, stream>>>(W3, BpW);
  k_wh_mfma<512, true><<<gW, 256, 0, stream>>>(hBb, BpW, Whb, as3, ad3, es, ed);
  k_edge_fused<4, 2><<<gE, 256, 0, stream>>>(rowptr, srcs, es, ed, Whb, nullptr, xb, N);
  k_gru_mfma<<<gW, 256, 0, stream>>>(xb, hBb, hB, Bih, Bhh, bih, bhh, hA, hAb);
  // ---- layer 4: H=1, GRU ----
  k_pack_w<128><<<(128 * 128 + 255) / 256, 256, 0, stream>>>(W4, BpW);
  k_wh_mfma<128, false><<<gW, 256, 0, stream>>>(hAb, BpW, Whb, nullptr, nullptr, nullptr, nullptr);
  k_es_ed1<<<(N + 3) / 4, 256, 0, stream>>>(Whb, as4, ad4, es, ed, N);
  k_edge_fused<1, 2><<<gE, 256, 0, stream>>>(rowptr, srcs, es, ed, Whb, nullptr, xb, N);
  k_gru_mfma<<<gW, 256, 0, stream>>>(xb, hAb, hA, Bih, Bhh, bih, bhh, hB, hBb);

  // ---- output head ----
  k_final<<<(N + 3) / 4, 256, 0, stream>>>(hB, W5, b5, (float*)d_out, N);
}